// Round 4
// baseline (1312.329 us; speedup 1.0000x reference)
//
#include <hip/hip_runtime.h>
#include <hip/hip_bf16.h>

#define B_ 2
#define L_ 1024
#define D_ 768
#define H_ 12
#define HD_ 64
#define NL_ 2
#define DFF_ 3072
#define V_ 50257
#define EOS_ 50256
#define TD_ (3 * D_)
#define BL_ (B_ * L_)

typedef __attribute__((ext_vector_type(8))) short bf16x8_t;
typedef __attribute__((ext_vector_type(4))) float f32x4_t;

#define AS1 __attribute__((address_space(1)))
#define AS3 __attribute__((address_space(3)))

__device__ __forceinline__ unsigned short f2bf(float f) {
  union { float f; unsigned int i; } c;
  c.f = f;
  unsigned int x = c.i;
  unsigned int lsb = (x >> 16) & 1u;
  x += 0x7fffu + lsb;
  return (unsigned short)(x >> 16);
}

// Async global->LDS, 16B per lane. LDS dest = wave-uniform base + lane*16.
__device__ __forceinline__ void gload_lds16(const void* g, void* l) {
  __builtin_amdgcn_global_load_lds((AS1 void*)(g), (AS3 void*)(l), 16, 0, 0);
}

// ---------------------------------------------------------------------------
// f32 -> bf16 bulk convert (vectorized by 4)
__global__ void cvt_kernel(const float* __restrict__ in,
                           unsigned short* __restrict__ out, int n4) {
  int i = blockIdx.x * blockDim.x + threadIdx.x;
  if (i >= n4) return;
  f32x4_t v = *(const f32x4_t*)(in + (size_t)i * 4);
  ushort4 o;
  o.x = f2bf(v[0]); o.y = f2bf(v[1]); o.z = f2bf(v[2]); o.w = f2bf(v[3]);
  *(ushort4*)(out + (size_t)i * 4) = o;
}

// ---------------------------------------------------------------------------
// rel[l] = l - last_eos_pos(<=l), l if none. Parallel backward scan per token.
__global__ void prep_kernel(const int* __restrict__ ids, int* __restrict__ rel) {
  int i = blockIdx.x * blockDim.x + threadIdx.x;
  if (i >= BL_) return;
  int b = i / L_, l = i % L_;
  const int* row = ids + (size_t)b * L_;
  int r = l;  // no eos before -> last=0 -> rel=l
  for (int j = l; j >= 0; --j) {
    if (row[j] == EOS_) { r = l - j; break; }
  }
  rel[i] = r;
}

// ---------------------------------------------------------------------------
// x = tok_emb[ids]*sqrt(D) + pos_emb[rel]; write f32 and bf16 shadow.
__global__ void embed_kernel(const int* __restrict__ ids,
                             const float* __restrict__ tok,
                             const float* __restrict__ pos,
                             const int* __restrict__ rel,
                             float* __restrict__ x,
                             unsigned short* __restrict__ xb) {
  int i = blockIdx.x * blockDim.x + threadIdx.x;
  if (i >= BL_ * D_) return;
  int d = i % D_;
  int bl = i / D_;
  int id = ids[bl];
  int r = rel[bl];
  float val = tok[(size_t)id * D_ + d] * 27.712812921102035f +
              pos[(size_t)r * D_ + d];
  x[i] = val;
  xb[i] = f2bf(val);
}

// ---------------------------------------------------------------------------
// LDS-staged GEMM (m97-ladder structure, single-buffer 2-barrier loop — the
// round-2 proven version; explicit 2-phase dbuf REGRESSED, see R3 post-mortem:
// 64KB LDS halved resident blocks and lost inter-block overlap).
// C[M,N] = A[M,K] @ W[N,K]^T + bias.  A,W bf16.
// Templates: BM/BN tile (128x128 for big grids, 64x64 to fill the machine on
// small-N GEMMs); ACT=1 -> bf16 gelu epilogue; NT=1 -> nontemporal f32 stores
// (pure-output streams, keep C from thrashing L2's W panels).
// 256 thr = 4 waves in 2x2; wave owns (BM/2)x(BN/2) (FMxFN 16x16 frags).
// Requires M%BM==0, K%64==0; N guarded.
template <int BM, int BN, int ACT, int NT>
__global__ __launch_bounds__(256) void gemm_tile_kernel(
    const unsigned short* __restrict__ A, const unsigned short* __restrict__ W,
    const float* __restrict__ bias, void* __restrict__ Cv,
    int M, int N, int K) {
  constexpr int WTM = BM / 2, WTN = BN / 2;   // wave tile
  constexpr int FM = WTM / 16, FN = WTN / 16; // frags per wave
  constexpr int PA = BM / 32, PB = BN / 32;   // staging passes (32 rows each)
  __shared__ unsigned short As[BM * 64];
  __shared__ unsigned short Bs[BN * 64];

  const int tid = threadIdx.x;
  const int wave = tid >> 6;
  const int lane = tid & 63;
  const int wr = wave >> 1;        // wave row 0..1
  const int wc = wave & 1;         // wave col 0..1
  const int lr = lane & 15;
  const int kq = (lane >> 4) << 3; // k element offset 0/8/16/24 within 32

  // XCD-aware bijective swizzle (m204), m-fastest within each XCD chunk:
  // blocks sharing a W-panel land contiguously on one XCD's L2.
  const int nwg = gridDim.x * gridDim.y;
  const int bidl = blockIdx.y * gridDim.x + blockIdx.x;
  const int xcd = bidl & 7;
  const int q8 = nwg >> 3, r8 = nwg & 7;
  const int lin = (xcd < r8 ? xcd * (q8 + 1)
                            : r8 * (q8 + 1) + (xcd - r8) * q8) + (bidl >> 3);
  const int m0 = (lin % gridDim.x) * BM;
  const int n0 = (lin / gridDim.x) * BN;

  // Staging: pass p, thread t writes LDS bytes [p*4096 + t*16, +16)
  // == row (p*32 + t/8), 16B slot (t&7) of a 128B row.
  // Swizzle: LDS slot s of row r holds global k-block (s ^ (r&7)).
  const int srow = tid >> 3;       // 0..31
  const int slot = tid & 7;
  const unsigned short* gA[PA];
  const unsigned short* gB[PB];
#pragma unroll
  for (int p = 0; p < PA; ++p) {
    int row = p * 32 + srow;
    int kblk = (slot ^ (row & 7)) << 3;           // element offset in K-tile
    gA[p] = A + (size_t)(m0 + row) * K + kblk;    // m0+row < M (M%BM==0)
  }
#pragma unroll
  for (int p = 0; p < PB; ++p) {
    int row = p * 32 + srow;
    int kblk = (slot ^ (row & 7)) << 3;
    int wrow = n0 + row;
    if (wrow >= N) wrow = N - 1;                  // clamp load; store guarded
    gB[p] = W + (size_t)wrow * K + kblk;
  }

  f32x4_t acc[FM][FN];
#pragma unroll
  for (int i = 0; i < FM; ++i)
#pragma unroll
    for (int j = 0; j < FN; ++j) acc[i][j] = (f32x4_t){0.f, 0.f, 0.f, 0.f};

  // Fragment rows: wr*WTM + i*16 + lr -> (row&7) == (lr&7) (all mult of 8)
  const int xmask = (lr & 7) << 4;                // byte-XOR swizzle mask
  const char* Ab = (const char*)As;
  const char* Bb = (const char*)Bs;

  for (int k0 = 0; k0 < K; k0 += 64) {
    if (k0) __syncthreads();                      // prev compute done
#pragma unroll
    for (int p = 0; p < PA; ++p)
      gload_lds16(gA[p] + k0, (char*)As + p * 4096 + wave * 1024);
#pragma unroll
    for (int p = 0; p < PB; ++p)
      gload_lds16(gB[p] + k0, (char*)Bs + p * 4096 + wave * 1024);
    __syncthreads();                              // drains vmcnt before barrier
#pragma unroll
    for (int ks = 0; ks < 2; ++ks) {
      const int kb = (ks << 6) + (kq << 1);       // byte offset of k-block
      bf16x8_t a[FM], b[FN];
#pragma unroll
      for (int i = 0; i < FM; ++i)
        a[i] = *(const bf16x8_t*)(Ab + (wr * WTM + i * 16 + lr) * 128 +
                                  (kb ^ xmask));
#pragma unroll
      for (int j = 0; j < FN; ++j)
        b[j] = *(const bf16x8_t*)(Bb + (wc * WTN + j * 16 + lr) * 128 +
                                  (kb ^ xmask));
#pragma unroll
      for (int i = 0; i < FM; ++i)
#pragma unroll
        for (int j = 0; j < FN; ++j)
          acc[i][j] =
              __builtin_amdgcn_mfma_f32_16x16x32_bf16(a[i], b[j], acc[i][j],
                                                      0, 0, 0);
    }
  }

  // C/D layout (m89/m91): col=lane&15, row=(lane>>4)*4+r
  const int crow0 = m0 + wr * WTM + ((lane >> 4) << 2);
#pragma unroll
  for (int i = 0; i < FM; ++i) {
    int crow = crow0 + i * 16;
#pragma unroll
    for (int j = 0; j < FN; ++j) {
      int col = n0 + wc * WTN + j * 16 + lr;
      if (col >= N) continue;
      float bv = bias ? bias[col] : 0.0f;
#pragma unroll
      for (int r = 0; r < 4; ++r) {
        float v = acc[i][j][r] + bv;
        if (ACT == 0) {
          float* cp = (float*)Cv + (size_t)(crow + r) * N + col;
          if (NT) __builtin_nontemporal_store(v, cp);
          else *cp = v;
        } else {
          float g = 0.5f * v * (1.f + erff(v * 0.7071067811865476f));
          ((unsigned short*)Cv)[(size_t)(crow + r) * N + col] = f2bf(g);
        }
      }
    }
  }
}

// ---------------------------------------------------------------------------
// Fallback GEMM (f32 W, inline cvt) — only used if workspace can't hold tok_b16.
template <int W_IS_F32>
__global__ __launch_bounds__(256) void gemm_bt_kernel(
    const unsigned short* __restrict__ A, const void* __restrict__ W,
    const float* __restrict__ bias, float* __restrict__ C,
    int M, int N, int K) {
  int wave = threadIdx.x >> 6;
  int lane = threadIdx.x & 63;
  int lr = lane & 15;
  int kq = (lane >> 4) << 3;
  int n0 = blockIdx.x << 6;
  int m0 = blockIdx.y << 6;
  int row = m0 + wave * 16 + lr;

  const unsigned short* arow = A + (size_t)row * K + kq;
  const unsigned short* browb[4];
  const float* browf[4];
#pragma unroll
  for (int nt = 0; nt < 4; ++nt) {
    int col = n0 + nt * 16 + lr;
    if (col >= N) col = N - 1;
    if (W_IS_F32) browf[nt] = (const float*)W + (size_t)col * K + kq;
    else          browb[nt] = (const unsigned short*)W + (size_t)col * K + kq;
  }

  f32x4_t acc[4] = {{0.f, 0.f, 0.f, 0.f},
                    {0.f, 0.f, 0.f, 0.f},
                    {0.f, 0.f, 0.f, 0.f},
                    {0.f, 0.f, 0.f, 0.f}};

  for (int k0 = 0; k0 < K; k0 += 32) {
    bf16x8_t a = *(const bf16x8_t*)(arow + k0);
#pragma unroll
    for (int nt = 0; nt < 4; ++nt) {
      bf16x8_t bfr;
      if (W_IS_F32) {
        f32x4_t w0 = *(const f32x4_t*)(browf[nt] + k0);
        f32x4_t w1 = *(const f32x4_t*)(browf[nt] + k0 + 4);
#pragma unroll
        for (int j = 0; j < 4; ++j) {
          bfr[j]     = (short)f2bf(w0[j]);
          bfr[4 + j] = (short)f2bf(w1[j]);
        }
      } else {
        bfr = *(const bf16x8_t*)(browb[nt] + k0);
      }
      acc[nt] = __builtin_amdgcn_mfma_f32_16x16x32_bf16(a, bfr, acc[nt], 0, 0, 0);
    }
  }

  int crow = m0 + wave * 16 + ((lane >> 4) << 2);
#pragma unroll
  for (int nt = 0; nt < 4; ++nt) {
    int col = n0 + nt * 16 + lr;
    if (col >= N) continue;
    float bv = bias ? bias[col] : 0.0f;
#pragma unroll
    for (int r = 0; r < 4; ++r) {
      float v = acc[nt][r] + bv;
      C[(size_t)(crow + r) * N + col] = v;
    }
  }
}

// ---------------------------------------------------------------------------
// MFMA flash attention. Block = 256 thr (4 waves) handles a 64-row Q-tile of
// one (b,h). Wave w owns q-rows qt0+w*16..+15. K-chunks of 64 staged in LDS:
// K as [key][d] bf16 (rows 144B, 16B-aligned), V transposed as [d][key] so the
// PV B-frag read (8 consecutive keys at fixed d) is a contiguous ds_read_b128.
// Online softmax in f32 on the C-frag layout (col=lane&15, row=hi*4+r);
// row-reduce via shfl_xor {8,4,2,1} within the 16-lane column group.
// P transits per-wave LDS to re-shape C-layout -> A-frag layout.
// Mask: key in [q - rel[q], q]; rel (cummax) is non-decreasing, so the tile's
// chunk range [align64(klo[qt0]) .. qt0+63] covers every row's valid keys.
__global__ __launch_bounds__(256) void attn_mfma_kernel(
    const float* __restrict__ qkv, const int* __restrict__ rel,
    unsigned short* __restrict__ obf) {
  __shared__ __align__(16) unsigned short k_s[64][72];
  __shared__ __align__(16) unsigned short v_s[64][72];
  __shared__ __align__(16) unsigned short p_s[4][16][72];

  const int tid = threadIdx.x;
  const int wave = tid >> 6, lane = tid & 63;
  const int lr = lane & 15, hi = lane >> 4;

  const int bid = blockIdx.x;
  const int qt0 = (bid & 15) << 6;     // L/64 = 16 q-tiles
  const int h = (bid >> 4) % H_;
  const int b = bid / (16 * H_);
  const int boff = b * L_;

  // Q fragments (f32 -> bf16): A-frag m=lane&15 -> q-row, k=hi*8+j -> d
  const int qrow = qt0 + wave * 16 + lr;
  const float* qp = qkv + (size_t)(boff + qrow) * TD_ + h * HD_ + hi * 8;
  bf16x8_t aq[2];
#pragma unroll
  for (int ks = 0; ks < 2; ++ks) {
    f32x4_t q0 = *(const f32x4_t*)(qp + ks * 32);
    f32x4_t q1 = *(const f32x4_t*)(qp + ks * 32 + 4);
#pragma unroll
    for (int j = 0; j < 4; ++j) {
      aq[ks][j] = (short)f2bf(q0[j]);
      aq[ks][4 + j] = (short)f2bf(q1[j]);
    }
  }

  // klo for the 4 accumulator rows this lane owns (C rows = hi*4+r)
  int klo_r[4];
#pragma unroll
  for (int r = 0; r < 4; ++r) {
    int qr = qt0 + wave * 16 + hi * 4 + r;
    klo_r[r] = qr - rel[boff + qr];
  }
  const int base0 = ((qt0 - rel[boff + qt0]) >> 6) << 6;

  float m_r[4] = {-1e30f, -1e30f, -1e30f, -1e30f};
  float l_r[4] = {0.f, 0.f, 0.f, 0.f};
  f32x4_t o_acc[4];
#pragma unroll
  for (int dt = 0; dt < 4; ++dt) o_acc[dt] = (f32x4_t){0.f, 0.f, 0.f, 0.f};

  const int skey = tid >> 2;           // staging: key row 0..63
  const int sdq = (tid & 3) << 4;      // staging: d quarter 0/16/32/48

  for (int base = base0; base <= qt0 + 63; base += 64) {
    __syncthreads();                   // prev chunk's LDS reads done
    // ---- stage K [key][d] and V^T [d][key], f32 -> bf16 (16 elems/thread ea)
    const float* kp = qkv + (size_t)(boff + base + skey) * TD_ + D_ +
                      h * HD_ + sdq;
    f32x4_t k0 = *(const f32x4_t*)(kp);
    f32x4_t k1 = *(const f32x4_t*)(kp + 4);
    f32x4_t k2 = *(const f32x4_t*)(kp + 8);
    f32x4_t k3 = *(const f32x4_t*)(kp + 12);
    bf16x8_t kb0, kb1;
#pragma unroll
    for (int j = 0; j < 4; ++j) {
      kb0[j] = (short)f2bf(k0[j]); kb0[4 + j] = (short)f2bf(k1[j]);
      kb1[j] = (short)f2bf(k2[j]); kb1[4 + j] = (short)f2bf(k3[j]);
    }
    *(bf16x8_t*)&k_s[skey][sdq] = kb0;
    *(bf16x8_t*)&k_s[skey][sdq + 8] = kb1;

    const float* vp = kp + D_;
    f32x4_t v0 = *(const f32x4_t*)(vp);
    f32x4_t v1 = *(const f32x4_t*)(vp + 4);
    f32x4_t v2 = *(const f32x4_t*)(vp + 8);
    f32x4_t v3 = *(const f32x4_t*)(vp + 12);
#pragma unroll
    for (int j = 0; j < 4; ++j) {
      v_s[sdq + j][skey]      = f2bf(v0[j]);
      v_s[sdq + 4 + j][skey]  = f2bf(v1[j]);
      v_s[sdq + 8 + j][skey]  = f2bf(v2[j]);
      v_s[sdq + 12 + j][skey] = f2bf(v3[j]);
    }
    __syncthreads();

    // ---- S = Q K^T : per wave 16 q-rows x 64 keys (4 tiles x 2 k-steps)
    f32x4_t s[4];
#pragma unroll
    for (int tj = 0; tj < 4; ++tj) {
      s[tj] = (f32x4_t){0.f, 0.f, 0.f, 0.f};
#pragma unroll
      for (int ks = 0; ks < 2; ++ks) {
        bf16x8_t kb = *(const bf16x8_t*)&k_s[tj * 16 + lr][ks * 32 + hi * 8];
        s[tj] = __builtin_amdgcn_mfma_f32_16x16x32_bf16(aq[ks], kb, s[tj],
                                                        0, 0, 0);
      }
    }

    // ---- online softmax (f32)
    float al_r[4];
#pragma unroll
    for (int r = 0; r < 4; ++r) {
      const int qr = qt0 + wave * 16 + hi * 4 + r;
#pragma unroll
      for (int tj = 0; tj < 4; ++tj) {
        int key = base + tj * 16 + lr;
        bool valid = (key >= klo_r[r]) && (key <= qr);
        s[tj][r] = valid ? s[tj][r] * 0.125f : -1e30f;
      }
      float cm = fmaxf(fmaxf(s[0][r], s[1][r]), fmaxf(s[2][r], s[3][r]));
#pragma unroll
      for (int off = 8; off; off >>= 1)
        cm = fmaxf(cm, __shfl_xor(cm, off, 64));
      float mn = fmaxf(m_r[r], cm);
      al_r[r] = __expf(m_r[r] - mn);   // both -1e30 -> exp(0)=1, o is 0 anyway
      float rs = 0.f;
#pragma unroll
      for (int tj = 0; tj < 4; ++tj) {
        float p = (s[tj][r] < -1e29f) ? 0.f : __expf(s[tj][r] - mn);
        s[tj][r] = p;
        rs += p;
      }
#pragma unroll
      for (int off = 8; off; off >>= 1) rs += __shfl_xor(rs, off, 64);
      l_r[r] = l_r[r] * al_r[r] + rs;
      m_r[r] = mn;
    }

    // ---- P (bf16) -> per-wave LDS (C-layout write, A-frag read); rescale O
#pragma unroll
    for (int r = 0; r < 4; ++r) {
#pragma unroll
      for (int tj = 0; tj < 4; ++tj)
        p_s[wave][hi * 4 + r][tj * 16 + lr] = f2bf(s[tj][r]);
#pragma unroll
      for (int dt = 0; dt < 4; ++dt) o_acc[dt][r] *= al_r[r];
    }
    // DS ops within a wave complete in order; compiler inserts lgkmcnt waits.

    // ---- O += P @ V  (B-frag from V^T layout: row d, 8 consecutive keys)
#pragma unroll
    for (int ks = 0; ks < 2; ++ks) {
      bf16x8_t pa = *(const bf16x8_t*)&p_s[wave][lr][ks * 32 + hi * 8];
#pragma unroll
      for (int dt = 0; dt < 4; ++dt) {
        bf16x8_t vb = *(const bf16x8_t*)&v_s[dt * 16 + lr][ks * 32 + hi * 8];
        o_acc[dt] = __builtin_amdgcn_mfma_f32_16x16x32_bf16(pa, vb, o_acc[dt],
                                                            0, 0, 0);
      }
    }
  }

  // ---- normalize and store (bf16)
#pragma unroll
  for (int r = 0; r < 4; ++r) {
    float inv = 1.f / l_r[r];
    int qr = qt0 + wave * 16 + hi * 4 + r;
    unsigned short* op = obf + (size_t)(boff + qr) * D_ + h * HD_ + lr;
#pragma unroll
    for (int dt = 0; dt < 4; ++dt)
      op[dt * 16] = f2bf(o_acc[dt][r] * inv);
  }
}

// ---------------------------------------------------------------------------
// x = LN(x + t)*w + b; write f32 and bf16 shadow. One block (256 thr) per row.
__device__ __forceinline__ float block_reduce_sum_256(float v, float* sbuf) {
#pragma unroll
  for (int off = 32; off; off >>= 1) v += __shfl_xor(v, off, 64);
  if ((threadIdx.x & 63) == 0) sbuf[threadIdx.x >> 6] = v;
  __syncthreads();
  float r = sbuf[0] + sbuf[1] + sbuf[2] + sbuf[3];
  __syncthreads();
  return r;
}

__global__ __launch_bounds__(256) void add_ln_kernel(
    const float* __restrict__ x, const float* __restrict__ t,
    const float* __restrict__ w, const float* __restrict__ b,
    float* __restrict__ xo, unsigned short* __restrict__ xbo) {
  __shared__ float sbuf[4];
  size_t base = (size_t)blockIdx.x * D_;
  float v[3];
  float s = 0.f;
#pragma unroll
  for (int i = 0; i < 3; ++i) {
    int idx = threadIdx.x + i * 256;
    v[i] = x[base + idx] + t[base + idx];
    s += v[i];
  }
  float mean = block_reduce_sum_256(s, sbuf) * (1.f / D_);
  float vs = 0.f;
#pragma unroll
  for (int i = 0; i < 3; ++i) {
    float d = v[i] - mean;
    vs += d * d;
  }
  float var = block_reduce_sum_256(vs, sbuf) * (1.f / D_);
  float rstd = rsqrtf(var + 1e-5f);
#pragma unroll
  for (int i = 0; i < 3; ++i) {
    int idx = threadIdx.x + i * 256;
    float o = (v[i] - mean) * rstd * w[idx] + b[idx];
    xo[base + idx] = o;
    xbo[base + idx] = f2bf(o);
  }
}

// ---------------------------------------------------------------------------
extern "C" void kernel_launch(void* const* d_in, const int* in_sizes, int n_in,
                              void* d_out, int out_size, void* d_ws, size_t ws_size,
                              hipStream_t stream) {
  const int* ids       = (const int*)d_in[0];
  const float* tok     = (const float*)d_in[1];
  const float* pos     = (const float*)d_in[2];
  const float* qkv_w   = (const float*)d_in[3];
  const float* qkv_b   = (const float*)d_in[4];
  const float* out_w   = (const float*)d_in[5];
  const float* out_b   = (const float*)d_in[6];
  const float* ln1_w   = (const float*)d_in[7];
  const float* ln1_b   = (const float*)d_in[8];
  const float* ln2_w   = (const float*)d_in[9];
  const float* ln2_b   = (const float*)d_in[10];
  const float* ff1_w   = (const float*)d_in[11];
  const float* ff2_w   = (const float*)d_in[13];
  const float* ff2_b   = (const float*)d_in[14];
  const float* ff1_b   = (const float*)d_in[12];

  char* ws = (char*)d_ws;
  size_t off = 0;
  auto alloc = [&](size_t bytes) {
    void* p = ws + off;
    off = (off + bytes + 255) & ~(size_t)255;
    return p;
  };
  int* rel            = (int*)alloc((size_t)BL_ * 4);
  float* x            = (float*)alloc((size_t)BL_ * D_ * 4);
  unsigned short* xb  = (unsigned short*)alloc((size_t)BL_ * D_ * 2);
  // qkvbuf (live qkv->attn) only user of big now
  float* big          = (float*)alloc((size_t)BL_ * DFF_ * 4);
  float* qkvbuf       = big;
  unsigned short* obf = (unsigned short*)alloc((size_t)BL_ * D_ * 2);
  float* t            = (float*)alloc((size_t)BL_ * D_ * 4);
  unsigned short* hb  = (unsigned short*)alloc((size_t)BL_ * DFF_ * 2);
  // bf16 weight copies (both layers)
  unsigned short* qkvw_b16 = (unsigned short*)alloc((size_t)NL_ * TD_ * D_ * 2);
  unsigned short* outw_b16 = (unsigned short*)alloc((size_t)NL_ * D_ * D_ * 2);
  unsigned short* ff1w_b16 = (unsigned short*)alloc((size_t)NL_ * DFF_ * D_ * 2);
  unsigned short* ff2w_b16 = (unsigned short*)alloc((size_t)NL_ * D_ * DFF_ * 2);
  size_t base_need = off;
  unsigned short* tok_b16 = (unsigned short*)alloc((size_t)V_ * D_ * 2);
  bool have_tok = (off <= ws_size);
  (void)base_need;

  auto cvt = [&](const float* in, unsigned short* out, size_t n) {
    int n4 = (int)(n / 4);
    cvt_kernel<<<(n4 + 255) / 256, 256, 0, stream>>>(in, out, n4);
  };
  cvt(qkv_w, qkvw_b16, (size_t)NL_ * TD_ * D_);
  cvt(out_w, outw_b16, (size_t)NL_ * D_ * D_);
  cvt(ff1_w, ff1w_b16, (size_t)NL_ * DFF_ * D_);
  cvt(ff2_w, ff2w_b16, (size_t)NL_ * D_ * DFF_);
  if (have_tok) cvt(tok, tok_b16, (size_t)V_ * D_);

  prep_kernel<<<(BL_ + 255) / 256, 256, 0, stream>>>(ids, rel);
  embed_kernel<<<(BL_ * D_ + 255) / 256, 256, 0, stream>>>(ids, tok, pos, rel, x, xb);

  // Tile choice: 128^2 for big grids; 64^2 when the 128^2 grid would leave
  // the machine under-filled (<384 blocks) and N is 64-aligned.
  auto gemm = [&](const unsigned short* A, const unsigned short* W,
                  const float* bias, float* C, int M, int N, int K) {
    int blocks128 = (M / 128) * ((N + 127) / 128);
    if ((N % 64) == 0 && blocks128 < 384) {
      gemm_tile_kernel<64, 64, 0, 0>
          <<<dim3(M / 64, N / 64), 256, 0, stream>>>(A, W, bias, (void*)C,
                                                     M, N, K);
    } else {
      gemm_tile_kernel<128, 128, 0, 0>
          <<<dim3(M / 128, (N + 127) / 128), 256, 0, stream>>>(
              A, W, bias, (void*)C, M, N, K);
    }
  };

  for (int l = 0; l < NL_; ++l) {
    // qkv = xb @ qkv_w[l].T + qkv_b[l]   [BL, 3D]
    gemm(xb, qkvw_b16 + (size_t)l * TD_ * D_, qkv_b + (size_t)l * TD_, qkvbuf,
         BL_, TD_, D_);
    // attention -> obf (bf16)
    attn_mfma_kernel<<<B_ * H_ * (L_ / 64), 256, 0, stream>>>(qkvbuf, rel, obf);
    // t = obf @ out_w[l].T + out_b[l]
    gemm(obf, outw_b16 + (size_t)l * D_ * D_, out_b + (size_t)l * D_, t,
         BL_, D_, D_);
    // x = LN(x + t)
    add_ln_kernel<<<BL_, 256, 0, stream>>>(x, t, ln1_w + l * D_, ln1_b + l * D_, x, xb);
    // hb = gelu(xb @ ff1_w[l].T + ff1_b[l]) in bf16, fused epilogue [BL, DFF]
    gemm_tile_kernel<128, 128, 1, 0>
        <<<dim3(BL_ / 128, DFF_ / 128), 256, 0, stream>>>(
            xb, ff1w_b16 + (size_t)l * DFF_ * D_, ff1_b + (size_t)l * DFF_,
            (void*)hb, BL_, DFF_, D_);
    // t = hb @ ff2_w[l].T + ff2_b[l]
    gemm(hb, ff2w_b16 + (size_t)l * D_ * DFF_, ff2_b + (size_t)l * D_, t,
         BL_, D_, DFF_);
    // x = LN(x + h)
    add_ln_kernel<<<BL_, 256, 0, stream>>>(x, t, ln2_w + l * D_, ln2_b + l * D_, x, xb);
  }

  // logits = xb @ tok_emb.T  -> f32 straight to d_out (nontemporal: pure
  // output stream, keep it from thrashing L2's W panels)  [BL, V]
  if (have_tok) {
    gemm_tile_kernel<128, 128, 0, 1>
        <<<dim3(BL_ / 128, (V_ + 127) / 128), 256, 0, stream>>>(
            xb, tok_b16, nullptr, (void*)d_out, BL_, V_, D_);
  } else {
    gemm_bt_kernel<1><<<dim3((V_ + 63) / 64, BL_ / 64), 256, 0, stream>>>(
        xb, tok, nullptr, (float*)d_out, BL_, V_, D_);
  }
}

// Round 5
// 1257.521 us; speedup vs baseline: 1.0436x; 1.0436x over previous
//
#include <hip/hip_runtime.h>
#include <hip/hip_bf16.h>

#define B_ 2
#define L_ 1024
#define D_ 768
#define H_ 12
#define HD_ 64
#define NL_ 2
#define DFF_ 3072
#define V_ 50257
#define EOS_ 50256
#define TD_ (3 * D_)
#define BL_ (B_ * L_)

typedef __attribute__((ext_vector_type(8))) short bf16x8_t;
typedef __attribute__((ext_vector_type(4))) float f32x4_t;

#define AS1 __attribute__((address_space(1)))
#define AS3 __attribute__((address_space(3)))

__device__ __forceinline__ unsigned short f2bf(float f) {
  union { float f; unsigned int i; } c;
  c.f = f;
  unsigned int x = c.i;
  unsigned int lsb = (x >> 16) & 1u;
  x += 0x7fffu + lsb;
  return (unsigned short)(x >> 16);
}

// Async global->LDS, 16B per lane. LDS dest = wave-uniform base + lane*16.
__device__ __forceinline__ void gload_lds16(const void* g, void* l) {
  __builtin_amdgcn_global_load_lds((AS1 void*)(g), (AS3 void*)(l), 16, 0, 0);
}

// ---------------------------------------------------------------------------
// f32 -> bf16 bulk convert (vectorized by 4)
__global__ void cvt_kernel(const float* __restrict__ in,
                           unsigned short* __restrict__ out, int n4) {
  int i = blockIdx.x * blockDim.x + threadIdx.x;
  if (i >= n4) return;
  f32x4_t v = *(const f32x4_t*)(in + (size_t)i * 4);
  ushort4 o;
  o.x = f2bf(v[0]); o.y = f2bf(v[1]); o.z = f2bf(v[2]); o.w = f2bf(v[3]);
  *(ushort4*)(out + (size_t)i * 4) = o;
}

// ---------------------------------------------------------------------------
// rel[l] = l - last_eos_pos(<=l), l if none. Parallel backward scan per token.
__global__ void prep_kernel(const int* __restrict__ ids, int* __restrict__ rel) {
  int i = blockIdx.x * blockDim.x + threadIdx.x;
  if (i >= BL_) return;
  int b = i / L_, l = i % L_;
  const int* row = ids + (size_t)b * L_;
  int r = l;  // no eos before -> last=0 -> rel=l
  for (int j = l; j >= 0; --j) {
    if (row[j] == EOS_) { r = l - j; break; }
  }
  rel[i] = r;
}

// ---------------------------------------------------------------------------
// x = tok_emb[ids]*sqrt(D) + pos_emb[rel]; write f32 and bf16 shadow.
__global__ void embed_kernel(const int* __restrict__ ids,
                             const float* __restrict__ tok,
                             const float* __restrict__ pos,
                             const int* __restrict__ rel,
                             float* __restrict__ x,
                             unsigned short* __restrict__ xb) {
  int i = blockIdx.x * blockDim.x + threadIdx.x;
  if (i >= BL_ * D_) return;
  int d = i % D_;
  int bl = i / D_;
  int id = ids[bl];
  int r = rel[bl];
  float val = tok[(size_t)id * D_ + d] * 27.712812921102035f +
              pos[(size_t)r * D_ + d];
  x[i] = val;
  xb[i] = f2bf(val);
}

// ---------------------------------------------------------------------------
// LDS-staged GEMM (m97-ladder structure, single-buffer 2-barrier loop — the
// proven version; explicit 2-phase dbuf REGRESSED (R3: 64KB LDS halved
// resident blocks); nontemporal C stores REGRESSED (R4: 1.7x HBM write
// amplification from partial-line writes)).
// C[M,N] = A[M,K] @ W[N,K]^T + bias.  A,W bf16.
// Tiles: 128x128 default; 64x64 to fill the machine on small-N GEMMs;
// 128x256 for the logits GEMM (2x MFMA:ds_read ratio, halves B traffic).
// ACT=1 -> bf16 gelu epilogue.
// 256 thr = 4 waves in 2x2; wave owns (BM/2)x(BN/2) (FMxFN 16x16 frags).
// Requires M%BM==0, K%64==0; N guarded.
template <int BM, int BN, int ACT>
__global__ __launch_bounds__(256) void gemm_tile_kernel(
    const unsigned short* __restrict__ A, const unsigned short* __restrict__ W,
    const float* __restrict__ bias, void* __restrict__ Cv,
    int M, int N, int K) {
  constexpr int WTM = BM / 2, WTN = BN / 2;   // wave tile
  constexpr int FM = WTM / 16, FN = WTN / 16; // frags per wave
  constexpr int PA = BM / 32, PB = BN / 32;   // staging passes (32 rows each)
  __shared__ unsigned short As[BM * 64];
  __shared__ unsigned short Bs[BN * 64];

  const int tid = threadIdx.x;
  const int wave = tid >> 6;
  const int lane = tid & 63;
  const int wr = wave >> 1;        // wave row 0..1
  const int wc = wave & 1;         // wave col 0..1
  const int lr = lane & 15;
  const int kq = (lane >> 4) << 3; // k element offset 0/8/16/24 within 32

  // XCD-aware bijective swizzle (m204), m-fastest within each XCD chunk:
  // blocks sharing a W-panel land contiguously on one XCD's L2.
  const int nwg = gridDim.x * gridDim.y;
  const int bidl = blockIdx.y * gridDim.x + blockIdx.x;
  const int xcd = bidl & 7;
  const int q8 = nwg >> 3, r8 = nwg & 7;
  const int lin = (xcd < r8 ? xcd * (q8 + 1)
                            : r8 * (q8 + 1) + (xcd - r8) * q8) + (bidl >> 3);
  const int m0 = (lin % gridDim.x) * BM;
  const int n0 = (lin / gridDim.x) * BN;

  // Staging: pass p, thread t writes LDS bytes [p*4096 + t*16, +16)
  // == row (p*32 + t/8), 16B slot (t&7) of a 128B row.
  // Swizzle: LDS slot s of row r holds global k-block (s ^ (r&7)).
  const int srow = tid >> 3;       // 0..31
  const int slot = tid & 7;
  const unsigned short* gA[PA];
  const unsigned short* gB[PB];
#pragma unroll
  for (int p = 0; p < PA; ++p) {
    int row = p * 32 + srow;
    int kblk = (slot ^ (row & 7)) << 3;           // element offset in K-tile
    gA[p] = A + (size_t)(m0 + row) * K + kblk;    // m0+row < M (M%BM==0)
  }
#pragma unroll
  for (int p = 0; p < PB; ++p) {
    int row = p * 32 + srow;
    int kblk = (slot ^ (row & 7)) << 3;
    int wrow = n0 + row;
    if (wrow >= N) wrow = N - 1;                  // clamp load; store guarded
    gB[p] = W + (size_t)wrow * K + kblk;
  }

  f32x4_t acc[FM][FN];
#pragma unroll
  for (int i = 0; i < FM; ++i)
#pragma unroll
    for (int j = 0; j < FN; ++j) acc[i][j] = (f32x4_t){0.f, 0.f, 0.f, 0.f};

  // Fragment rows: wr*WTM + i*16 + lr -> (row&7) == (lr&7) (all mult of 8)
  const int xmask = (lr & 7) << 4;                // byte-XOR swizzle mask
  const char* Ab = (const char*)As;
  const char* Bb = (const char*)Bs;

  for (int k0 = 0; k0 < K; k0 += 64) {
    if (k0) __syncthreads();                      // prev compute done
#pragma unroll
    for (int p = 0; p < PA; ++p)
      gload_lds16(gA[p] + k0, (char*)As + p * 4096 + wave * 1024);
#pragma unroll
    for (int p = 0; p < PB; ++p)
      gload_lds16(gB[p] + k0, (char*)Bs + p * 4096 + wave * 1024);
    __syncthreads();                              // drains vmcnt before barrier
#pragma unroll
    for (int ks = 0; ks < 2; ++ks) {
      const int kb = (ks << 6) + (kq << 1);       // byte offset of k-block
      bf16x8_t a[FM], b[FN];
#pragma unroll
      for (int i = 0; i < FM; ++i)
        a[i] = *(const bf16x8_t*)(Ab + (wr * WTM + i * 16 + lr) * 128 +
                                  (kb ^ xmask));
#pragma unroll
      for (int j = 0; j < FN; ++j)
        b[j] = *(const bf16x8_t*)(Bb + (wc * WTN + j * 16 + lr) * 128 +
                                  (kb ^ xmask));
#pragma unroll
      for (int i = 0; i < FM; ++i)
#pragma unroll
        for (int j = 0; j < FN; ++j)
          acc[i][j] =
              __builtin_amdgcn_mfma_f32_16x16x32_bf16(a[i], b[j], acc[i][j],
                                                      0, 0, 0);
    }
  }

  // C/D layout (m89/m91): col=lane&15, row=(lane>>4)*4+r
  const int crow0 = m0 + wr * WTM + ((lane >> 4) << 2);
#pragma unroll
  for (int i = 0; i < FM; ++i) {
    int crow = crow0 + i * 16;
#pragma unroll
    for (int j = 0; j < FN; ++j) {
      int col = n0 + wc * WTN + j * 16 + lr;
      if (col >= N) continue;
      float bv = bias ? bias[col] : 0.0f;
#pragma unroll
      for (int r = 0; r < 4; ++r) {
        float v = acc[i][j][r] + bv;
        if (ACT == 0) {
          ((float*)Cv)[(size_t)(crow + r) * N + col] = v;
        } else {
          float g = 0.5f * v * (1.f + erff(v * 0.7071067811865476f));
          ((unsigned short*)Cv)[(size_t)(crow + r) * N + col] = f2bf(g);
        }
      }
    }
  }
}

// ---------------------------------------------------------------------------
// Fallback GEMM (f32 W, inline cvt) — only used if workspace can't hold tok_b16.
template <int W_IS_F32>
__global__ __launch_bounds__(256) void gemm_bt_kernel(
    const unsigned short* __restrict__ A, const void* __restrict__ W,
    const float* __restrict__ bias, float* __restrict__ C,
    int M, int N, int K) {
  int wave = threadIdx.x >> 6;
  int lane = threadIdx.x & 63;
  int lr = lane & 15;
  int kq = (lane >> 4) << 3;
  int n0 = blockIdx.x << 6;
  int m0 = blockIdx.y << 6;
  int row = m0 + wave * 16 + lr;

  const unsigned short* arow = A + (size_t)row * K + kq;
  const unsigned short* browb[4];
  const float* browf[4];
#pragma unroll
  for (int nt = 0; nt < 4; ++nt) {
    int col = n0 + nt * 16 + lr;
    if (col >= N) col = N - 1;
    if (W_IS_F32) browf[nt] = (const float*)W + (size_t)col * K + kq;
    else          browb[nt] = (const unsigned short*)W + (size_t)col * K + kq;
  }

  f32x4_t acc[4] = {{0.f, 0.f, 0.f, 0.f},
                    {0.f, 0.f, 0.f, 0.f},
                    {0.f, 0.f, 0.f, 0.f},
                    {0.f, 0.f, 0.f, 0.f}};

  for (int k0 = 0; k0 < K; k0 += 32) {
    bf16x8_t a = *(const bf16x8_t*)(arow + k0);
#pragma unroll
    for (int nt = 0; nt < 4; ++nt) {
      bf16x8_t bfr;
      if (W_IS_F32) {
        f32x4_t w0 = *(const f32x4_t*)(browf[nt] + k0);
        f32x4_t w1 = *(const f32x4_t*)(browf[nt] + k0 + 4);
#pragma unroll
        for (int j = 0; j < 4; ++j) {
          bfr[j]     = (short)f2bf(w0[j]);
          bfr[4 + j] = (short)f2bf(w1[j]);
        }
      } else {
        bfr = *(const bf16x8_t*)(browb[nt] + k0);
      }
      acc[nt] = __builtin_amdgcn_mfma_f32_16x16x32_bf16(a, bfr, acc[nt], 0, 0, 0);
    }
  }

  int crow = m0 + wave * 16 + ((lane >> 4) << 2);
#pragma unroll
  for (int nt = 0; nt < 4; ++nt) {
    int col = n0 + nt * 16 + lr;
    if (col >= N) continue;
    float bv = bias ? bias[col] : 0.0f;
#pragma unroll
    for (int r = 0; r < 4; ++r) {
      float v = acc[nt][r] + bv;
      C[(size_t)(crow + r) * N + col] = v;
    }
  }
}

// ---------------------------------------------------------------------------
// MFMA flash attention. Block = 256 thr (4 waves) handles a 64-row Q-tile of
// one (b,h). Wave w owns q-rows qt0+w*16..+15. K-chunks of 64 staged in LDS:
// K as [key][d] bf16 (rows 144B, 16B-aligned), V transposed as [d][key] so the
// PV B-frag read (8 consecutive keys at fixed d) is a contiguous ds_read_b128.
// Online softmax in f32 on the C-frag layout (col=lane&15, row=hi*4+r);
// row-reduce via shfl_xor {8,4,2,1} within the 16-lane column group.
// P transits per-wave LDS to re-shape C-layout -> A-frag layout.
// Mask: key in [q - rel[q], q]; rel (cummax) is non-decreasing, so the tile's
// chunk range [align64(klo[qt0]) .. qt0+63] covers every row's valid keys.
__global__ __launch_bounds__(256) void attn_mfma_kernel(
    const float* __restrict__ qkv, const int* __restrict__ rel,
    unsigned short* __restrict__ obf) {
  __shared__ __align__(16) unsigned short k_s[64][72];
  __shared__ __align__(16) unsigned short v_s[64][72];
  __shared__ __align__(16) unsigned short p_s[4][16][72];

  const int tid = threadIdx.x;
  const int wave = tid >> 6, lane = tid & 63;
  const int lr = lane & 15, hi = lane >> 4;

  const int bid = blockIdx.x;
  const int qt0 = (bid & 15) << 6;     // L/64 = 16 q-tiles
  const int h = (bid >> 4) % H_;
  const int b = bid / (16 * H_);
  const int boff = b * L_;

  // Q fragments (f32 -> bf16): A-frag m=lane&15 -> q-row, k=hi*8+j -> d
  const int qrow = qt0 + wave * 16 + lr;
  const float* qp = qkv + (size_t)(boff + qrow) * TD_ + h * HD_ + hi * 8;
  bf16x8_t aq[2];
#pragma unroll
  for (int ks = 0; ks < 2; ++ks) {
    f32x4_t q0 = *(const f32x4_t*)(qp + ks * 32);
    f32x4_t q1 = *(const f32x4_t*)(qp + ks * 32 + 4);
#pragma unroll
    for (int j = 0; j < 4; ++j) {
      aq[ks][j] = (short)f2bf(q0[j]);
      aq[ks][4 + j] = (short)f2bf(q1[j]);
    }
  }

  // klo for the 4 accumulator rows this lane owns (C rows = hi*4+r)
  int klo_r[4];
#pragma unroll
  for (int r = 0; r < 4; ++r) {
    int qr = qt0 + wave * 16 + hi * 4 + r;
    klo_r[r] = qr - rel[boff + qr];
  }
  const int base0 = ((qt0 - rel[boff + qt0]) >> 6) << 6;

  float m_r[4] = {-1e30f, -1e30f, -1e30f, -1e30f};
  float l_r[4] = {0.f, 0.f, 0.f, 0.f};
  f32x4_t o_acc[4];
#pragma unroll
  for (int dt = 0; dt < 4; ++dt) o_acc[dt] = (f32x4_t){0.f, 0.f, 0.f, 0.f};

  const int skey = tid >> 2;           // staging: key row 0..63
  const int sdq = (tid & 3) << 4;      // staging: d quarter 0/16/32/48

  for (int base = base0; base <= qt0 + 63; base += 64) {
    __syncthreads();                   // prev chunk's LDS reads done
    // ---- stage K [key][d] and V^T [d][key], f32 -> bf16 (16 elems/thread ea)
    const float* kp = qkv + (size_t)(boff + base + skey) * TD_ + D_ +
                      h * HD_ + sdq;
    f32x4_t k0 = *(const f32x4_t*)(kp);
    f32x4_t k1 = *(const f32x4_t*)(kp + 4);
    f32x4_t k2 = *(const f32x4_t*)(kp + 8);
    f32x4_t k3 = *(const f32x4_t*)(kp + 12);
    bf16x8_t kb0, kb1;
#pragma unroll
    for (int j = 0; j < 4; ++j) {
      kb0[j] = (short)f2bf(k0[j]); kb0[4 + j] = (short)f2bf(k1[j]);
      kb1[j] = (short)f2bf(k2[j]); kb1[4 + j] = (short)f2bf(k3[j]);
    }
    *(bf16x8_t*)&k_s[skey][sdq] = kb0;
    *(bf16x8_t*)&k_s[skey][sdq + 8] = kb1;

    const float* vp = kp + D_;
    f32x4_t v0 = *(const f32x4_t*)(vp);
    f32x4_t v1 = *(const f32x4_t*)(vp + 4);
    f32x4_t v2 = *(const f32x4_t*)(vp + 8);
    f32x4_t v3 = *(const f32x4_t*)(vp + 12);
#pragma unroll
    for (int j = 0; j < 4; ++j) {
      v_s[sdq + j][skey]      = f2bf(v0[j]);
      v_s[sdq + 4 + j][skey]  = f2bf(v1[j]);
      v_s[sdq + 8 + j][skey]  = f2bf(v2[j]);
      v_s[sdq + 12 + j][skey] = f2bf(v3[j]);
    }
    __syncthreads();

    // ---- S = Q K^T : per wave 16 q-rows x 64 keys (4 tiles x 2 k-steps)
    f32x4_t s[4];
#pragma unroll
    for (int tj = 0; tj < 4; ++tj) {
      s[tj] = (f32x4_t){0.f, 0.f, 0.f, 0.f};
#pragma unroll
      for (int ks = 0; ks < 2; ++ks) {
        bf16x8_t kb = *(const bf16x8_t*)&k_s[tj * 16 + lr][ks * 32 + hi * 8];
        s[tj] = __builtin_amdgcn_mfma_f32_16x16x32_bf16(aq[ks], kb, s[tj],
                                                        0, 0, 0);
      }
    }

    // ---- online softmax (f32)
    float al_r[4];
#pragma unroll
    for (int r = 0; r < 4; ++r) {
      const int qr = qt0 + wave * 16 + hi * 4 + r;
#pragma unroll
      for (int tj = 0; tj < 4; ++tj) {
        int key = base + tj * 16 + lr;
        bool valid = (key >= klo_r[r]) && (key <= qr);
        s[tj][r] = valid ? s[tj][r] * 0.125f : -1e30f;
      }
      float cm = fmaxf(fmaxf(s[0][r], s[1][r]), fmaxf(s[2][r], s[3][r]));
#pragma unroll
      for (int off = 8; off; off >>= 1)
        cm = fmaxf(cm, __shfl_xor(cm, off, 64));
      float mn = fmaxf(m_r[r], cm);
      al_r[r] = __expf(m_r[r] - mn);   // both -1e30 -> exp(0)=1, o is 0 anyway
      float rs = 0.f;
#pragma unroll
      for (int tj = 0; tj < 4; ++tj) {
        float p = (s[tj][r] < -1e29f) ? 0.f : __expf(s[tj][r] - mn);
        s[tj][r] = p;
        rs += p;
      }
#pragma unroll
      for (int off = 8; off; off >>= 1) rs += __shfl_xor(rs, off, 64);
      l_r[r] = l_r[r] * al_r[r] + rs;
      m_r[r] = mn;
    }

    // ---- P (bf16) -> per-wave LDS (C-layout write, A-frag read); rescale O
#pragma unroll
    for (int r = 0; r < 4; ++r) {
#pragma unroll
      for (int tj = 0; tj < 4; ++tj)
        p_s[wave][hi * 4 + r][tj * 16 + lr] = f2bf(s[tj][r]);
#pragma unroll
      for (int dt = 0; dt < 4; ++dt) o_acc[dt][r] *= al_r[r];
    }
    // DS ops within a wave complete in order; compiler inserts lgkmcnt waits.

    // ---- O += P @ V  (B-frag from V^T layout: row d, 8 consecutive keys)
#pragma unroll
    for (int ks = 0; ks < 2; ++ks) {
      bf16x8_t pa = *(const bf16x8_t*)&p_s[wave][lr][ks * 32 + hi * 8];
#pragma unroll
      for (int dt = 0; dt < 4; ++dt) {
        bf16x8_t vb = *(const bf16x8_t*)&v_s[dt * 16 + lr][ks * 32 + hi * 8];
        o_acc[dt] = __builtin_amdgcn_mfma_f32_16x16x32_bf16(pa, vb, o_acc[dt],
                                                            0, 0, 0);
      }
    }
  }

  // ---- normalize and store (bf16)
#pragma unroll
  for (int r = 0; r < 4; ++r) {
    float inv = 1.f / l_r[r];
    int qr = qt0 + wave * 16 + hi * 4 + r;
    unsigned short* op = obf + (size_t)(boff + qr) * D_ + h * HD_ + lr;
#pragma unroll
    for (int dt = 0; dt < 4; ++dt)
      op[dt * 16] = f2bf(o_acc[dt][r] * inv);
  }
}

// ---------------------------------------------------------------------------
// x = LN(x + t)*w + b; write f32 and bf16 shadow. One block (256 thr) per row.
__device__ __forceinline__ float block_reduce_sum_256(float v, float* sbuf) {
#pragma unroll
  for (int off = 32; off; off >>= 1) v += __shfl_xor(v, off, 64);
  if ((threadIdx.x & 63) == 0) sbuf[threadIdx.x >> 6] = v;
  __syncthreads();
  float r = sbuf[0] + sbuf[1] + sbuf[2] + sbuf[3];
  __syncthreads();
  return r;
}

__global__ __launch_bounds__(256) void add_ln_kernel(
    const float* __restrict__ x, const float* __restrict__ t,
    const float* __restrict__ w, const float* __restrict__ b,
    float* __restrict__ xo, unsigned short* __restrict__ xbo) {
  __shared__ float sbuf[4];
  size_t base = (size_t)blockIdx.x * D_;
  float v[3];
  float s = 0.f;
#pragma unroll
  for (int i = 0; i < 3; ++i) {
    int idx = threadIdx.x + i * 256;
    v[i] = x[base + idx] + t[base + idx];
    s += v[i];
  }
  float mean = block_reduce_sum_256(s, sbuf) * (1.f / D_);
  float vs = 0.f;
#pragma unroll
  for (int i = 0; i < 3; ++i) {
    float d = v[i] - mean;
    vs += d * d;
  }
  float var = block_reduce_sum_256(vs, sbuf) * (1.f / D_);
  float rstd = rsqrtf(var + 1e-5f);
#pragma unroll
  for (int i = 0; i < 3; ++i) {
    int idx = threadIdx.x + i * 256;
    float o = (v[i] - mean) * rstd * w[idx] + b[idx];
    xo[base + idx] = o;
    xbo[base + idx] = f2bf(o);
  }
}

// ---------------------------------------------------------------------------
extern "C" void kernel_launch(void* const* d_in, const int* in_sizes, int n_in,
                              void* d_out, int out_size, void* d_ws, size_t ws_size,
                              hipStream_t stream) {
  const int* ids       = (const int*)d_in[0];
  const float* tok     = (const float*)d_in[1];
  const float* pos     = (const float*)d_in[2];
  const float* qkv_w   = (const float*)d_in[3];
  const float* qkv_b   = (const float*)d_in[4];
  const float* out_w   = (const float*)d_in[5];
  const float* out_b   = (const float*)d_in[6];
  const float* ln1_w   = (const float*)d_in[7];
  const float* ln1_b   = (const float*)d_in[8];
  const float* ln2_w   = (const float*)d_in[9];
  const float* ln2_b   = (const float*)d_in[10];
  const float* ff1_w   = (const float*)d_in[11];
  const float* ff2_w   = (const float*)d_in[13];
  const float* ff2_b   = (const float*)d_in[14];
  const float* ff1_b   = (const float*)d_in[12];

  char* ws = (char*)d_ws;
  size_t off = 0;
  auto alloc = [&](size_t bytes) {
    void* p = ws + off;
    off = (off + bytes + 255) & ~(size_t)255;
    return p;
  };
  int* rel            = (int*)alloc((size_t)BL_ * 4);
  float* x            = (float*)alloc((size_t)BL_ * D_ * 4);
  unsigned short* xb  = (unsigned short*)alloc((size_t)BL_ * D_ * 2);
  // qkvbuf (live qkv->attn) only user of big now
  float* big          = (float*)alloc((size_t)BL_ * DFF_ * 4);
  float* qkvbuf       = big;
  unsigned short* obf = (unsigned short*)alloc((size_t)BL_ * D_ * 2);
  float* t            = (float*)alloc((size_t)BL_ * D_ * 4);
  unsigned short* hb  = (unsigned short*)alloc((size_t)BL_ * DFF_ * 2);
  // bf16 weight copies (both layers)
  unsigned short* qkvw_b16 = (unsigned short*)alloc((size_t)NL_ * TD_ * D_ * 2);
  unsigned short* outw_b16 = (unsigned short*)alloc((size_t)NL_ * D_ * D_ * 2);
  unsigned short* ff1w_b16 = (unsigned short*)alloc((size_t)NL_ * DFF_ * D_ * 2);
  unsigned short* ff2w_b16 = (unsigned short*)alloc((size_t)NL_ * D_ * DFF_ * 2);
  size_t base_need = off;
  unsigned short* tok_b16 = (unsigned short*)alloc((size_t)V_ * D_ * 2);
  bool have_tok = (off <= ws_size);
  (void)base_need;

  auto cvt = [&](const float* in, unsigned short* out, size_t n) {
    int n4 = (int)(n / 4);
    cvt_kernel<<<(n4 + 255) / 256, 256, 0, stream>>>(in, out, n4);
  };
  cvt(qkv_w, qkvw_b16, (size_t)NL_ * TD_ * D_);
  cvt(out_w, outw_b16, (size_t)NL_ * D_ * D_);
  cvt(ff1_w, ff1w_b16, (size_t)NL_ * DFF_ * D_);
  cvt(ff2_w, ff2w_b16, (size_t)NL_ * D_ * DFF_);
  if (have_tok) cvt(tok, tok_b16, (size_t)V_ * D_);

  prep_kernel<<<(BL_ + 255) / 256, 256, 0, stream>>>(ids, rel);
  embed_kernel<<<(BL_ * D_ + 255) / 256, 256, 0, stream>>>(ids, tok, pos, rel, x, xb);

  // Tile choice: 128^2 for big grids; 64^2 when the 128^2 grid would leave
  // the machine under-filled (<384 blocks) and N is 64-aligned.
  auto gemm = [&](const unsigned short* A, const unsigned short* W,
                  const float* bias, float* C, int M, int N, int K) {
    int blocks128 = (M / 128) * ((N + 127) / 128);
    if ((N % 64) == 0 && blocks128 < 384) {
      gemm_tile_kernel<64, 64, 0>
          <<<dim3(M / 64, N / 64), 256, 0, stream>>>(A, W, bias, (void*)C,
                                                     M, N, K);
    } else {
      gemm_tile_kernel<128, 128, 0>
          <<<dim3(M / 128, (N + 127) / 128), 256, 0, stream>>>(
              A, W, bias, (void*)C, M, N, K);
    }
  };

  for (int l = 0; l < NL_; ++l) {
    // qkv = xb @ qkv_w[l].T + qkv_b[l]   [BL, 3D]
    gemm(xb, qkvw_b16 + (size_t)l * TD_ * D_, qkv_b + (size_t)l * TD_, qkvbuf,
         BL_, TD_, D_);
    // attention -> obf (bf16)
    attn_mfma_kernel<<<B_ * H_ * (L_ / 64), 256, 0, stream>>>(qkvbuf, rel, obf);
    // t = obf @ out_w[l].T + out_b[l]
    gemm(obf, outw_b16 + (size_t)l * D_ * D_, out_b + (size_t)l * D_, t,
         BL_, D_, D_);
    // x = LN(x + t)
    add_ln_kernel<<<BL_, 256, 0, stream>>>(x, t, ln1_w + l * D_, ln1_b + l * D_, x, xb);
    // hb = gelu(xb @ ff1_w[l].T + ff1_b[l]) in bf16, fused epilogue [BL, DFF]
    gemm_tile_kernel<128, 128, 1>
        <<<dim3(BL_ / 128, DFF_ / 128), 256, 0, stream>>>(
            xb, ff1w_b16 + (size_t)l * DFF_ * D_, ff1_b + (size_t)l * DFF_,
            (void*)hb, BL_, DFF_, D_);
    // t = hb @ ff2_w[l].T + ff2_b[l]
    gemm(hb, ff2w_b16 + (size_t)l * D_ * DFF_, ff2_b + (size_t)l * D_, t,
         BL_, D_, DFF_);
    // x = LN(x + h)
    add_ln_kernel<<<BL_, 256, 0, stream>>>(x, t, ln2_w + l * D_, ln2_b + l * D_, x, xb);
  }

  // logits = xb @ tok_emb.T  -> f32 straight to d_out  [BL, V]
  // 128x256 tile: 2x MFMA:ds_read ratio vs 128^2, halves B-panel traffic.
  if (have_tok) {
    gemm_tile_kernel<128, 256, 0>
        <<<dim3(BL_ / 128, (V_ + 255) / 256), 256, 0, stream>>>(
            xb, tok_b16, nullptr, (void*)d_out, BL_, V_, D_);
  } else {
    gemm_bt_kernel<1><<<dim3((V_ + 63) / 64, BL_ / 64), 256, 0, stream>>>(
        xb, tok, nullptr, (float*)d_out, BL_, V_, D_);
  }
}

// Round 7
// 1122.877 us; speedup vs baseline: 1.1687x; 1.1199x over previous
//
#include <hip/hip_runtime.h>
#include <hip/hip_bf16.h>

#define B_ 2
#define L_ 1024
#define D_ 768
#define H_ 12
#define HD_ 64
#define NL_ 2
#define DFF_ 3072
#define V_ 50257
#define EOS_ 50256
#define TD_ (3 * D_)
#define BL_ (B_ * L_)

typedef __attribute__((ext_vector_type(8))) short bf16x8_t;
typedef __attribute__((ext_vector_type(4))) float f32x4_t;

#define AS1 __attribute__((address_space(1)))
#define AS3 __attribute__((address_space(3)))

__device__ __forceinline__ unsigned short f2bf(float f) {
  union { float f; unsigned int i; } c;
  c.f = f;
  unsigned int x = c.i;
  unsigned int lsb = (x >> 16) & 1u;
  x += 0x7fffu + lsb;
  return (unsigned short)(x >> 16);
}

// Async global->LDS, 16B per lane. LDS dest = wave-uniform base + lane*16.
__device__ __forceinline__ void gload_lds16(const void* g, void* l) {
  __builtin_amdgcn_global_load_lds((AS1 void*)(g), (AS3 void*)(l), 16, 0, 0);
}

// ---------------------------------------------------------------------------
// f32 -> bf16 bulk convert (vectorized by 4)
__global__ void cvt_kernel(const float* __restrict__ in,
                           unsigned short* __restrict__ out, int n4) {
  int i = blockIdx.x * blockDim.x + threadIdx.x;
  if (i >= n4) return;
  f32x4_t v = *(const f32x4_t*)(in + (size_t)i * 4);
  ushort4 o;
  o.x = f2bf(v[0]); o.y = f2bf(v[1]); o.z = f2bf(v[2]); o.w = f2bf(v[3]);
  *(ushort4*)(out + (size_t)i * 4) = o;
}

// ---------------------------------------------------------------------------
// rel[l] = l - last_eos_pos(<=l), l if none. Parallel backward scan per token.
__global__ void prep_kernel(const int* __restrict__ ids, int* __restrict__ rel) {
  int i = blockIdx.x * blockDim.x + threadIdx.x;
  if (i >= BL_) return;
  int b = i / L_, l = i % L_;
  const int* row = ids + (size_t)b * L_;
  int r = l;  // no eos before -> last=0 -> rel=l
  for (int j = l; j >= 0; --j) {
    if (row[j] == EOS_) { r = l - j; break; }
  }
  rel[i] = r;
}

// ---------------------------------------------------------------------------
// x = tok_emb[ids]*sqrt(D) + pos_emb[rel]; write f32 and bf16 shadow.
__global__ void embed_kernel(const int* __restrict__ ids,
                             const float* __restrict__ tok,
                             const float* __restrict__ pos,
                             const int* __restrict__ rel,
                             float* __restrict__ x,
                             unsigned short* __restrict__ xb) {
  int i = blockIdx.x * blockDim.x + threadIdx.x;
  if (i >= BL_ * D_) return;
  int d = i % D_;
  int bl = i / D_;
  int id = ids[bl];
  int r = rel[bl];
  float val = tok[(size_t)id * D_ + d] * 27.712812921102035f +
              pos[(size_t)r * D_ + d];
  x[i] = val;
  xb[i] = f2bf(val);
}

// ---------------------------------------------------------------------------
// LDS-staged GEMM. C[M,N] = A[M,K] @ W[N,K]^T + bias.  A,W bf16.
// Ledger of structural A/Bs on this template:
//  - 128^2 single-buffer 2-barrier: PROVEN (R2: logits 307us, MfmaUtil 21.5).
//  - 128^2 + dbuf (64KB LDS): REGRESSED (R3: occupancy 5->2 blocks/CU).
//  - 128x256 (48KB LDS, 136 VGPR): REGRESSED (R5: ~1 block/CU).
//  - nontemporal C stores: REGRESSED (R4: 1.7x HBM write amplification).
//  => 32KB LDS / >=5 blocks-per-CU capability is the operating point.
//  - DBUF=1 on 64^2 tiles keeps LDS at 2x(8+8)=32KB: pipeline the per-K-step
//    vmcnt drain (the dominant cost of small-tile latency-bound GEMMs) with
//    counted vmcnt(4) + raw s_barrier (R3-verified-correct structure).
// ACT=1 -> bf16 gelu epilogue. 256 thr = 4 waves 2x2; wave owns
// (BM/2)x(BN/2). Requires M%BM==0, K%64==0; N guarded.
template <int BM, int BN, int ACT, int DBUF>
__global__ __launch_bounds__(256) void gemm_tile_kernel(
    const unsigned short* __restrict__ A, const unsigned short* __restrict__ W,
    const float* __restrict__ bias, void* __restrict__ Cv,
    int M, int N, int K) {
  constexpr int WTM = BM / 2, WTN = BN / 2;   // wave tile
  constexpr int FM = WTM / 16, FN = WTN / 16; // frags per wave
  constexpr int PA = BM / 32, PB = BN / 32;   // staging passes (32 rows each)
  constexpr int NB = DBUF ? 2 : 1;
  __shared__ unsigned short As[NB][BM * 64];
  __shared__ unsigned short Bs[NB][BN * 64];

  const int tid = threadIdx.x;
  const int wave = tid >> 6;
  const int lane = tid & 63;
  const int wr = wave >> 1;        // wave row 0..1
  const int wc = wave & 1;         // wave col 0..1
  const int lr = lane & 15;
  const int kq = (lane >> 4) << 3; // k element offset 0/8/16/24 within 32

  // XCD-aware bijective swizzle (m204), m-fastest within each XCD chunk:
  // blocks sharing a W-panel land contiguously on one XCD's L2.
  const int nwg = gridDim.x * gridDim.y;
  const int bidl = blockIdx.y * gridDim.x + blockIdx.x;
  const int xcd = bidl & 7;
  const int q8 = nwg >> 3, r8 = nwg & 7;
  const int lin = (xcd < r8 ? xcd * (q8 + 1)
                            : r8 * (q8 + 1) + (xcd - r8) * q8) + (bidl >> 3);
  const int m0 = (lin % gridDim.x) * BM;
  const int n0 = (lin / gridDim.x) * BN;

  // Staging: pass p, thread t writes LDS bytes [p*4096 + t*16, +16)
  // == row (p*32 + t/8), 16B slot (t&7) of a 128B row.
  // Swizzle: LDS slot s of row r holds global k-block (s ^ (r&7)).
  const int srow = tid >> 3;       // 0..31
  const int slot = tid & 7;
  const unsigned short* gA[PA];
  const unsigned short* gB[PB];
#pragma unroll
  for (int p = 0; p < PA; ++p) {
    int row = p * 32 + srow;
    int kblk = (slot ^ (row & 7)) << 3;           // element offset in K-tile
    gA[p] = A + (size_t)(m0 + row) * K + kblk;    // m0+row < M (M%BM==0)
  }
#pragma unroll
  for (int p = 0; p < PB; ++p) {
    int row = p * 32 + srow;
    int kblk = (slot ^ (row & 7)) << 3;
    int wrow = n0 + row;
    if (wrow >= N) wrow = N - 1;                  // clamp load; store guarded
    gB[p] = W + (size_t)wrow * K + kblk;
  }

  f32x4_t acc[FM][FN];
#pragma unroll
  for (int i = 0; i < FM; ++i)
#pragma unroll
    for (int j = 0; j < FN; ++j) acc[i][j] = (f32x4_t){0.f, 0.f, 0.f, 0.f};

  // Fragment rows: wr*WTM + i*16 + lr -> (row&7) == (lr&7) (all mult of 8)
  const int xmask = (lr & 7) << 4;                // byte-XOR swizzle mask
  const int NKT = K >> 6;

  auto stage = [&](int buf, int kt) {
    const int k0 = kt << 6;
#pragma unroll
    for (int p = 0; p < PA; ++p)
      gload_lds16(gA[p] + k0, (char*)As[buf] + p * 4096 + wave * 1024);
#pragma unroll
    for (int p = 0; p < PB; ++p)
      gload_lds16(gB[p] + k0, (char*)Bs[buf] + p * 4096 + wave * 1024);
  };

  auto compute = [&](int buf) {
    const char* Ab = (const char*)As[buf];
    const char* Bb = (const char*)Bs[buf];
#pragma unroll
    for (int ks = 0; ks < 2; ++ks) {
      const int kb = (ks << 6) + (kq << 1);       // byte offset of k-block
      bf16x8_t a[FM], b[FN];
#pragma unroll
      for (int i = 0; i < FM; ++i)
        a[i] = *(const bf16x8_t*)(Ab + (wr * WTM + i * 16 + lr) * 128 +
                                  (kb ^ xmask));
#pragma unroll
      for (int j = 0; j < FN; ++j)
        b[j] = *(const bf16x8_t*)(Bb + (wc * WTN + j * 16 + lr) * 128 +
                                  (kb ^ xmask));
#pragma unroll
      for (int i = 0; i < FM; ++i)
#pragma unroll
        for (int j = 0; j < FN; ++j)
          acc[i][j] =
              __builtin_amdgcn_mfma_f32_16x16x32_bf16(a[i], b[j], acc[i][j],
                                                      0, 0, 0);
    }
  };

  if (DBUF) {
    // 2-phase counted-vmcnt pipeline (R3-verified structure).
    // Race-freedom: every ds_read feeds an MFMA before barrier S2, so all
    // reads of buf[cur] complete before any wave passes S2; overwrite of
    // buf[cur] is issued after S2. vmcnt(LOADS)+S1 guarantees tile kt's
    // loads landed in all waves before any wave reads it.
    stage(0, 0);
    int cur = 0;
    for (int kt = 0; kt < NKT; ++kt) {
      if (kt + 1 < NKT) {
        stage(cur ^ 1, kt + 1);
        if constexpr (PA + PB == 4)
          asm volatile("s_waitcnt vmcnt(4)" ::: "memory");
        else
          asm volatile("s_waitcnt vmcnt(8)" ::: "memory");
      } else {
        asm volatile("s_waitcnt vmcnt(0)" ::: "memory");
      }
      __builtin_amdgcn_s_barrier();               // S1: tile kt visible
      __builtin_amdgcn_sched_barrier(0);
      compute(cur);
      __builtin_amdgcn_sched_barrier(0);
      __builtin_amdgcn_s_barrier();               // S2: reads of buf done
      cur ^= 1;
    }
  } else {
    // Single-buffer 2-barrier loop (proven baseline).
    for (int kt = 0; kt < NKT; ++kt) {
      if (kt) __syncthreads();
      stage(0, kt);
      __syncthreads();                            // drains vmcnt
      compute(0);
    }
  }

  // C/D layout (m89/m91): col=lane&15, row=(lane>>4)*4+r
  const int crow0 = m0 + wr * WTM + ((lane >> 4) << 2);
#pragma unroll
  for (int i = 0; i < FM; ++i) {
    int crow = crow0 + i * 16;
#pragma unroll
    for (int j = 0; j < FN; ++j) {
      int col = n0 + wc * WTN + j * 16 + lr;
      if (col >= N) continue;
      float bv = bias ? bias[col] : 0.0f;
#pragma unroll
      for (int r = 0; r < 4; ++r) {
        float v = acc[i][j][r] + bv;
        if (ACT == 0) {
          ((float*)Cv)[(size_t)(crow + r) * N + col] = v;
        } else {
          float g = 0.5f * v * (1.f + erff(v * 0.7071067811865476f));
          ((unsigned short*)Cv)[(size_t)(crow + r) * N + col] = f2bf(g);
        }
      }
    }
  }
}

// ---------------------------------------------------------------------------
// Fallback GEMM (f32 W, inline cvt) — only used if workspace can't hold tok_b16.
template <int W_IS_F32>
__global__ __launch_bounds__(256) void gemm_bt_kernel(
    const unsigned short* __restrict__ A, const void* __restrict__ W,
    const float* __restrict__ bias, float* __restrict__ C,
    int M, int N, int K) {
  int wave = threadIdx.x >> 6;
  int lane = threadIdx.x & 63;
  int lr = lane & 15;
  int kq = (lane >> 4) << 3;
  int n0 = blockIdx.x << 6;
  int m0 = blockIdx.y << 6;
  int row = m0 + wave * 16 + lr;

  const unsigned short* arow = A + (size_t)row * K + kq;
  const unsigned short* browb[4];
  const float* browf[4];
#pragma unroll
  for (int nt = 0; nt < 4; ++nt) {
    int col = n0 + nt * 16 + lr;
    if (col >= N) col = N - 1;
    if (W_IS_F32) browf[nt] = (const float*)W + (size_t)col * K + kq;
    else          browb[nt] = (const unsigned short*)W + (size_t)col * K + kq;
  }

  f32x4_t acc[4] = {{0.f, 0.f, 0.f, 0.f},
                    {0.f, 0.f, 0.f, 0.f},
                    {0.f, 0.f, 0.f, 0.f},
                    {0.f, 0.f, 0.f, 0.f}};

  for (int k0 = 0; k0 < K; k0 += 32) {
    bf16x8_t a = *(const bf16x8_t*)(arow + k0);
#pragma unroll
    for (int nt = 0; nt < 4; ++nt) {
      bf16x8_t bfr;
      if (W_IS_F32) {
        f32x4_t w0 = *(const f32x4_t*)(browf[nt] + k0);
        f32x4_t w1 = *(const f32x4_t*)(browf[nt] + k0 + 4);
#pragma unroll
        for (int j = 0; j < 4; ++j) {
          bfr[j]     = (short)f2bf(w0[j]);
          bfr[4 + j] = (short)f2bf(w1[j]);
        }
      } else {
        bfr = *(const bf16x8_t*)(browb[nt] + k0);
      }
      acc[nt] = __builtin_amdgcn_mfma_f32_16x16x32_bf16(a, bfr, acc[nt], 0, 0, 0);
    }
  }

  int crow = m0 + wave * 16 + ((lane >> 4) << 2);
#pragma unroll
  for (int nt = 0; nt < 4; ++nt) {
    int col = n0 + nt * 16 + lr;
    if (col >= N) continue;
    float bv = bias ? bias[col] : 0.0f;
#pragma unroll
    for (int r = 0; r < 4; ++r) {
      float v = acc[nt][r] + bv;
      C[(size_t)(crow + r) * N + col] = v;
    }
  }
}

// ---------------------------------------------------------------------------
// MFMA flash attention. Block = 256 thr (4 waves) handles a 64-row Q-tile of
// one (b,h). Wave w owns q-rows qt0+w*16..+15. K-chunks of 64 staged in LDS:
// K as [key][d] bf16 (rows 144B, 16B-aligned), V transposed as [d][key] so the
// PV B-frag read (8 consecutive keys at fixed d) is a contiguous ds_read_b128.
// Online softmax in f32 on the C-frag layout (col=lane&15, row=hi*4+r);
// row-reduce via shfl_xor {8,4,2,1} within the 16-lane column group.
// P transits per-wave LDS to re-shape C-layout -> A-frag layout.
// Mask: key in [q - rel[q], q]; rel (cummax) is non-decreasing, so the tile's
// chunk range [align64(klo[qt0]) .. qt0+63] covers every row's valid keys.
__global__ __launch_bounds__(256) void attn_mfma_kernel(
    const float* __restrict__ qkv, const int* __restrict__ rel,
    unsigned short* __restrict__ obf) {
  __shared__ __align__(16) unsigned short k_s[64][72];
  __shared__ __align__(16) unsigned short v_s[64][72];
  __shared__ __align__(16) unsigned short p_s[4][16][72];

  const int tid = threadIdx.x;
  const int wave = tid >> 6, lane = tid & 63;
  const int lr = lane & 15, hi = lane >> 4;

  const int bid = blockIdx.x;
  const int qt0 = (bid & 15) << 6;     // L/64 = 16 q-tiles
  const int h = (bid >> 4) % H_;
  const int b = bid / (16 * H_);
  const int boff = b * L_;

  // Q fragments (f32 -> bf16): A-frag m=lane&15 -> q-row, k=hi*8+j -> d
  const int qrow = qt0 + wave * 16 + lr;
  const float* qp = qkv + (size_t)(boff + qrow) * TD_ + h * HD_ + hi * 8;
  bf16x8_t aq[2];
#pragma unroll
  for (int ks = 0; ks < 2; ++ks) {
    f32x4_t q0 = *(const f32x4_t*)(qp + ks * 32);
    f32x4_t q1 = *(const f32x4_t*)(qp + ks * 32 + 4);
#pragma unroll
    for (int j = 0; j < 4; ++j) {
      aq[ks][j] = (short)f2bf(q0[j]);
      aq[ks][4 + j] = (short)f2bf(q1[j]);
    }
  }

  // klo for the 4 accumulator rows this lane owns (C rows = hi*4+r)
  int klo_r[4];
#pragma unroll
  for (int r = 0; r < 4; ++r) {
    int qr = qt0 + wave * 16 + hi * 4 + r;
    klo_r[r] = qr - rel[boff + qr];
  }
  const int base0 = ((qt0 - rel[boff + qt0]) >> 6) << 6;

  float m_r[4] = {-1e30f, -1e30f, -1e30f, -1e30f};
  float l_r[4] = {0.f, 0.f, 0.f, 0.f};
  f32x4_t o_acc[4];
#pragma unroll
  for (int dt = 0; dt < 4; ++dt) o_acc[dt] = (f32x4_t){0.f, 0.f, 0.f, 0.f};

  const int skey = tid >> 2;           // staging: key row 0..63
  const int sdq = (tid & 3) << 4;      // staging: d quarter 0/16/32/48

  for (int base = base0; base <= qt0 + 63; base += 64) {
    __syncthreads();                   // prev chunk's LDS reads done
    // ---- stage K [key][d] and V^T [d][key], f32 -> bf16 (16 elems/thread ea)
    const float* kp = qkv + (size_t)(boff + base + skey) * TD_ + D_ +
                      h * HD_ + sdq;
    f32x4_t k0 = *(const f32x4_t*)(kp);
    f32x4_t k1 = *(const f32x4_t*)(kp + 4);
    f32x4_t k2 = *(const f32x4_t*)(kp + 8);
    f32x4_t k3 = *(const f32x4_t*)(kp + 12);
    bf16x8_t kb0, kb1;
#pragma unroll
    for (int j = 0; j < 4; ++j) {
      kb0[j] = (short)f2bf(k0[j]); kb0[4 + j] = (short)f2bf(k1[j]);
      kb1[j] = (short)f2bf(k2[j]); kb1[4 + j] = (short)f2bf(k3[j]);
    }
    *(bf16x8_t*)&k_s[skey][sdq] = kb0;
    *(bf16x8_t*)&k_s[skey][sdq + 8] = kb1;

    const float* vp = kp + D_;
    f32x4_t v0 = *(const f32x4_t*)(vp);
    f32x4_t v1 = *(const f32x4_t*)(vp + 4);
    f32x4_t v2 = *(const f32x4_t*)(vp + 8);
    f32x4_t v3 = *(const f32x4_t*)(vp + 12);
#pragma unroll
    for (int j = 0; j < 4; ++j) {
      v_s[sdq + j][skey]      = f2bf(v0[j]);
      v_s[sdq + 4 + j][skey]  = f2bf(v1[j]);
      v_s[sdq + 8 + j][skey]  = f2bf(v2[j]);
      v_s[sdq + 12 + j][skey] = f2bf(v3[j]);
    }
    __syncthreads();

    // ---- S = Q K^T : per wave 16 q-rows x 64 keys (4 tiles x 2 k-steps)
    f32x4_t s[4];
#pragma unroll
    for (int tj = 0; tj < 4; ++tj) {
      s[tj] = (f32x4_t){0.f, 0.f, 0.f, 0.f};
#pragma unroll
      for (int ks = 0; ks < 2; ++ks) {
        bf16x8_t kb = *(const bf16x8_t*)&k_s[tj * 16 + lr][ks * 32 + hi * 8];
        s[tj] = __builtin_amdgcn_mfma_f32_16x16x32_bf16(aq[ks], kb, s[tj],
                                                        0, 0, 0);
      }
    }

    // ---- online softmax (f32)
    float al_r[4];
#pragma unroll
    for (int r = 0; r < 4; ++r) {
      const int qr = qt0 + wave * 16 + hi * 4 + r;
#pragma unroll
      for (int tj = 0; tj < 4; ++tj) {
        int key = base + tj * 16 + lr;
        bool valid = (key >= klo_r[r]) && (key <= qr);
        s[tj][r] = valid ? s[tj][r] * 0.125f : -1e30f;
      }
      float cm = fmaxf(fmaxf(s[0][r], s[1][r]), fmaxf(s[2][r], s[3][r]));
#pragma unroll
      for (int off = 8; off; off >>= 1)
        cm = fmaxf(cm, __shfl_xor(cm, off, 64));
      float mn = fmaxf(m_r[r], cm);
      al_r[r] = __expf(m_r[r] - mn);   // both -1e30 -> exp(0)=1, o is 0 anyway
      float rs = 0.f;
#pragma unroll
      for (int tj = 0; tj < 4; ++tj) {
        float p = (s[tj][r] < -1e29f) ? 0.f : __expf(s[tj][r] - mn);
        s[tj][r] = p;
        rs += p;
      }
#pragma unroll
      for (int off = 8; off; off >>= 1) rs += __shfl_xor(rs, off, 64);
      l_r[r] = l_r[r] * al_r[r] + rs;
      m_r[r] = mn;
    }

    // ---- P (bf16) -> per-wave LDS (C-layout write, A-frag read); rescale O
#pragma unroll
    for (int r = 0; r < 4; ++r) {
#pragma unroll
      for (int tj = 0; tj < 4; ++tj)
        p_s[wave][hi * 4 + r][tj * 16 + lr] = f2bf(s[tj][r]);
#pragma unroll
      for (int dt = 0; dt < 4; ++dt) o_acc[dt][r] *= al_r[r];
    }
    // DS ops within a wave complete in order; compiler inserts lgkmcnt waits.

    // ---- O += P @ V  (B-frag from V^T layout: row d, 8 consecutive keys)
#pragma unroll
    for (int ks = 0; ks < 2; ++ks) {
      bf16x8_t pa = *(const bf16x8_t*)&p_s[wave][lr][ks * 32 + hi * 8];
#pragma unroll
      for (int dt = 0; dt < 4; ++dt) {
        bf16x8_t vb = *(const bf16x8_t*)&v_s[dt * 16 + lr][ks * 32 + hi * 8];
        o_acc[dt] = __builtin_amdgcn_mfma_f32_16x16x32_bf16(pa, vb, o_acc[dt],
                                                            0, 0, 0);
      }
    }
  }

  // ---- normalize and store (bf16)
#pragma unroll
  for (int r = 0; r < 4; ++r) {
    float inv = 1.f / l_r[r];
    int qr = qt0 + wave * 16 + hi * 4 + r;
    unsigned short* op = obf + (size_t)(boff + qr) * D_ + h * HD_ + lr;
#pragma unroll
    for (int dt = 0; dt < 4; ++dt)
      op[dt * 16] = f2bf(o_acc[dt][r] * inv);
  }
}

// ---------------------------------------------------------------------------
// x = LN(x + t)*w + b; write f32 and bf16 shadow. One block (256 thr) per row.
__device__ __forceinline__ float block_reduce_sum_256(float v, float* sbuf) {
#pragma unroll
  for (int off = 32; off; off >>= 1) v += __shfl_xor(v, off, 64);
  if ((threadIdx.x & 63) == 0) sbuf[threadIdx.x >> 6] = v;
  __syncthreads();
  float r = sbuf[0] + sbuf[1] + sbuf[2] + sbuf[3];
  __syncthreads();
  return r;
}

__global__ __launch_bounds__(256) void add_ln_kernel(
    const float* __restrict__ x, const float* __restrict__ t,
    const float* __restrict__ w, const float* __restrict__ b,
    float* __restrict__ xo, unsigned short* __restrict__ xbo) {
  __shared__ float sbuf[4];
  size_t base = (size_t)blockIdx.x * D_;
  float v[3];
  float s = 0.f;
#pragma unroll
  for (int i = 0; i < 3; ++i) {
    int idx = threadIdx.x + i * 256;
    v[i] = x[base + idx] + t[base + idx];
    s += v[i];
  }
  float mean = block_reduce_sum_256(s, sbuf) * (1.f / D_);
  float vs = 0.f;
#pragma unroll
  for (int i = 0; i < 3; ++i) {
    float d = v[i] - mean;
    vs += d * d;
  }
  float var = block_reduce_sum_256(vs, sbuf) * (1.f / D_);
  float rstd = rsqrtf(var + 1e-5f);
#pragma unroll
  for (int i = 0; i < 3; ++i) {
    int idx = threadIdx.x + i * 256;
    float o = (v[i] - mean) * rstd * w[idx] + b[idx];
    xo[base + idx] = o;
    xbo[base + idx] = f2bf(o);
  }
}

// ---------------------------------------------------------------------------
extern "C" void kernel_launch(void* const* d_in, const int* in_sizes, int n_in,
                              void* d_out, int out_size, void* d_ws, size_t ws_size,
                              hipStream_t stream) {
  const int* ids       = (const int*)d_in[0];
  const float* tok     = (const float*)d_in[1];
  const float* pos     = (const float*)d_in[2];
  const float* qkv_w   = (const float*)d_in[3];
  const float* qkv_b   = (const float*)d_in[4];
  const float* out_w   = (const float*)d_in[5];
  const float* out_b   = (const float*)d_in[6];
  const float* ln1_w   = (const float*)d_in[7];
  const float* ln1_b   = (const float*)d_in[8];
  const float* ln2_w   = (const float*)d_in[9];
  const float* ln2_b   = (const float*)d_in[10];
  const float* ff1_w   = (const float*)d_in[11];
  const float* ff2_w   = (const float*)d_in[13];
  const float* ff2_b   = (const float*)d_in[14];
  const float* ff1_b   = (const float*)d_in[12];

  char* ws = (char*)d_ws;
  size_t off = 0;
  auto alloc = [&](size_t bytes) {
    void* p = ws + off;
    off = (off + bytes + 255) & ~(size_t)255;
    return p;
  };
  int* rel            = (int*)alloc((size_t)BL_ * 4);
  float* x            = (float*)alloc((size_t)BL_ * D_ * 4);
  unsigned short* xb  = (unsigned short*)alloc((size_t)BL_ * D_ * 2);
  // qkvbuf (live qkv->attn) only user of big now
  float* big          = (float*)alloc((size_t)BL_ * DFF_ * 4);
  float* qkvbuf       = big;
  unsigned short* obf = (unsigned short*)alloc((size_t)BL_ * D_ * 2);
  float* t            = (float*)alloc((size_t)BL_ * D_ * 4);
  unsigned short* hb  = (unsigned short*)alloc((size_t)BL_ * DFF_ * 2);
  // bf16 weight copies (both layers)
  unsigned short* qkvw_b16 = (unsigned short*)alloc((size_t)NL_ * TD_ * D_ * 2);
  unsigned short* outw_b16 = (unsigned short*)alloc((size_t)NL_ * D_ * D_ * 2);
  unsigned short* ff1w_b16 = (unsigned short*)alloc((size_t)NL_ * DFF_ * D_ * 2);
  unsigned short* ff2w_b16 = (unsigned short*)alloc((size_t)NL_ * D_ * DFF_ * 2);
  size_t base_need = off;
  unsigned short* tok_b16 = (unsigned short*)alloc((size_t)V_ * D_ * 2);
  bool have_tok = (off <= ws_size);
  (void)base_need;

  auto cvt = [&](const float* in, unsigned short* out, size_t n) {
    int n4 = (int)(n / 4);
    cvt_kernel<<<(n4 + 255) / 256, 256, 0, stream>>>(in, out, n4);
  };
  cvt(qkv_w, qkvw_b16, (size_t)NL_ * TD_ * D_);
  cvt(out_w, outw_b16, (size_t)NL_ * D_ * D_);
  cvt(ff1_w, ff1w_b16, (size_t)NL_ * DFF_ * D_);
  cvt(ff2_w, ff2w_b16, (size_t)NL_ * D_ * DFF_);
  if (have_tok) cvt(tok, tok_b16, (size_t)V_ * D_);

  prep_kernel<<<(BL_ + 255) / 256, 256, 0, stream>>>(ids, rel);
  embed_kernel<<<(BL_ * D_ + 255) / 256, 256, 0, stream>>>(ids, tok, pos, rel, x, xb);

  // Tile choice: 128^2 single-buffer for big grids; 64^2 + DBUF pipeline
  // when the 128^2 grid would under-fill the machine (<384 blocks).
  auto gemm = [&](const unsigned short* A, const unsigned short* W,
                  const float* bias, float* C, int M, int N, int K) {
    int blocks128 = (M / 128) * ((N + 127) / 128);
    if ((N % 64) == 0 && blocks128 < 384) {
      gemm_tile_kernel<64, 64, 0, 1>
          <<<dim3(M / 64, N / 64), 256, 0, stream>>>(A, W, bias, (void*)C,
                                                     M, N, K);
    } else {
      gemm_tile_kernel<128, 128, 0, 0>
          <<<dim3(M / 128, (N + 127) / 128), 256, 0, stream>>>(
              A, W, bias, (void*)C, M, N, K);
    }
  };

  for (int l = 0; l < NL_; ++l) {
    // qkv = xb @ qkv_w[l].T + qkv_b[l]   [BL, 3D]
    gemm(xb, qkvw_b16 + (size_t)l * TD_ * D_, qkv_b + (size_t)l * TD_, qkvbuf,
         BL_, TD_, D_);
    // attention -> obf (bf16)
    attn_mfma_kernel<<<B_ * H_ * (L_ / 64), 256, 0, stream>>>(qkvbuf, rel, obf);
    // t = obf @ out_w[l].T + out_b[l]
    gemm(obf, outw_b16 + (size_t)l * D_ * D_, out_b + (size_t)l * D_, t,
         BL_, D_, D_);
    // x = LN(x + t)
    add_ln_kernel<<<BL_, 256, 0, stream>>>(x, t, ln1_w + l * D_, ln1_b + l * D_, x, xb);
    // hb = gelu(xb @ ff1_w[l].T + ff1_b[l]) in bf16, fused epilogue [BL, DFF]
    gemm_tile_kernel<128, 128, 1, 0>
        <<<dim3(BL_ / 128, DFF_ / 128), 256, 0, stream>>>(
            xb, ff1w_b16 + (size_t)l * DFF_ * D_, ff1_b + (size_t)l * DFF_,
            (void*)hb, BL_, DFF_, D_);
    // t = hb @ ff2_w[l].T + ff2_b[l]
    gemm(hb, ff2w_b16 + (size_t)l * D_ * DFF_, ff2_b + (size_t)l * D_, t,
         BL_, D_, DFF_);
    // x = LN(x + h)
    add_ln_kernel<<<BL_, 256, 0, stream>>>(x, t, ln2_w + l * D_, ln2_b + l * D_, x, xb);
  }

  // logits = xb @ tok_emb.T  -> f32 straight to d_out  [BL, V]
  // (128^2 single-buffer: R2-proven config for this dispatch)
  if (have_tok) {
    gemm_tile_kernel<128, 128, 0, 0>
        <<<dim3(BL_ / 128, (V_ + 127) / 128), 256, 0, stream>>>(
            xb, tok_b16, nullptr, (void*)d_out, BL_, V_, D_);
  } else {
    gemm_bt_kernel<1><<<dim3((V_ + 63) / 64, BL_ / 64), 256, 0, stream>>>(
        xb, tok, nullptr, (float*)d_out, BL_, V_, D_);
  }
}

// Round 8
// 1000.354 us; speedup vs baseline: 1.3119x; 1.1225x over previous
//
#include <hip/hip_runtime.h>
#include <hip/hip_bf16.h>

#define B_ 2
#define L_ 1024
#define D_ 768
#define H_ 12
#define HD_ 64
#define NL_ 2
#define DFF_ 3072
#define V_ 50257
#define EOS_ 50256
#define TD_ (3 * D_)
#define BL_ (B_ * L_)

typedef __attribute__((ext_vector_type(8))) short bf16x8_t;
typedef __attribute__((ext_vector_type(4))) float f32x4_t;

#define AS1 __attribute__((address_space(1)))
#define AS3 __attribute__((address_space(3)))

__device__ __forceinline__ unsigned short f2bf(float f) {
  union { float f; unsigned int i; } c;
  c.f = f;
  unsigned int x = c.i;
  unsigned int lsb = (x >> 16) & 1u;
  x += 0x7fffu + lsb;
  return (unsigned short)(x >> 16);
}

// Async global->LDS, 16B per lane. LDS dest = wave-uniform base + lane*16.
__device__ __forceinline__ void gload_lds16(const void* g, void* l) {
  __builtin_amdgcn_global_load_lds((AS1 void*)(g), (AS3 void*)(l), 16, 0, 0);
}

// ---------------------------------------------------------------------------
// f32 -> bf16 bulk convert (vectorized by 4)
__global__ void cvt_kernel(const float* __restrict__ in,
                           unsigned short* __restrict__ out, int n4) {
  int i = blockIdx.x * blockDim.x + threadIdx.x;
  if (i >= n4) return;
  f32x4_t v = *(const f32x4_t*)(in + (size_t)i * 4);
  ushort4 o;
  o.x = f2bf(v[0]); o.y = f2bf(v[1]); o.z = f2bf(v[2]); o.w = f2bf(v[3]);
  *(ushort4*)(out + (size_t)i * 4) = o;
}

// ---------------------------------------------------------------------------
// rel[l] = l - last_eos_pos(<=l), l if none. Parallel backward scan per token.
__global__ void prep_kernel(const int* __restrict__ ids, int* __restrict__ rel) {
  int i = blockIdx.x * blockDim.x + threadIdx.x;
  if (i >= BL_) return;
  int b = i / L_, l = i % L_;
  const int* row = ids + (size_t)b * L_;
  int r = l;  // no eos before -> last=0 -> rel=l
  for (int j = l; j >= 0; --j) {
    if (row[j] == EOS_) { r = l - j; break; }
  }
  rel[i] = r;
}

// ---------------------------------------------------------------------------
// x = tok_emb[ids]*sqrt(D) + pos_emb[rel]; write f32 and bf16 shadow.
__global__ void embed_kernel(const int* __restrict__ ids,
                             const float* __restrict__ tok,
                             const float* __restrict__ pos,
                             const int* __restrict__ rel,
                             float* __restrict__ x,
                             unsigned short* __restrict__ xb) {
  int i = blockIdx.x * blockDim.x + threadIdx.x;
  if (i >= BL_ * D_) return;
  int d = i % D_;
  int bl = i / D_;
  int id = ids[bl];
  int r = rel[bl];
  float val = tok[(size_t)id * D_ + d] * 27.712812921102035f +
              pos[(size_t)r * D_ + d];
  x[i] = val;
  xb[i] = f2bf(val);
}

// ---------------------------------------------------------------------------
// LDS-staged GEMM. C[M,N] = A[M,K] @ W[N,K]^T + bias.  A,W bf16.
// Ledger of structural A/Bs on this template:
//  - 128^2 single-buffer 2-barrier: PROVEN (R2/R7: logits 285-307us).
//  - 128^2 + dbuf (64KB LDS): REGRESSED (R3: occupancy 5->2 blocks/CU).
//  - 128x256 (48KB LDS, 136 VGPR): REGRESSED (R5: ~1 block/CU).
//  - raw nt frag stores: REGRESSED (R4: 1.7x HBM write amplification from
//    64B half-line stores) BUT proved nt keeps W in L2 (FETCH 266->96 MB).
//  - 64^2+DBUF counted-vmcnt: NEUTRAL (R7 vs R5: non-logits 823->838).
//    Third confirmation of guide m99/m131: source dbuf on 2-barrier = null.
//  => 32KB LDS / high-blocks-per-CU is the operating point; keep DBUF=1 on
//    64^2 only because it is measured-neutral and already verified.
// ACT=0: f32 C. ACT=1: bf16 gelu(C). ACT=2 (128^2 only, bias=null): f32 C
//   via LDS transpose + FULL-LINE nontemporal stores — captures R4's fetch
//   win without its write amplification (1024B contiguous per instruction).
// 256 thr = 4 waves 2x2; wave owns (BM/2)x(BN/2). M%BM==0, K%64==0; N guarded.
template <int BM, int BN, int ACT, int DBUF>
__global__ __launch_bounds__(256) void gemm_tile_kernel(
    const unsigned short* __restrict__ A, const unsigned short* __restrict__ W,
    const float* __restrict__ bias, void* __restrict__ Cv,
    int M, int N, int K) {
  constexpr int WTM = BM / 2, WTN = BN / 2;   // wave tile
  constexpr int FM = WTM / 16, FN = WTN / 16; // frags per wave
  constexpr int PA = BM / 32, PB = BN / 32;   // staging passes (32 rows each)
  constexpr int NB = DBUF ? 2 : 1;
  // Flat smem: staging (NB*(BM+BN)*64 ushorts = 32KB for all instantiations);
  // ACT==2 reuses it post-K-loop as float[64][128] (exactly 32KB).
  __shared__ __align__(16) unsigned short smem[NB * (BM + BN) * 64];
  unsigned short* Asb = smem;                  // [NB][BM*64]
  unsigned short* Bsb = smem + NB * BM * 64;   // [NB][BN*64]

  const int tid = threadIdx.x;
  const int wave = tid >> 6;
  const int lane = tid & 63;
  const int wr = wave >> 1;        // wave row 0..1
  const int wc = wave & 1;         // wave col 0..1
  const int lr = lane & 15;
  const int kq = (lane >> 4) << 3; // k element offset 0/8/16/24 within 32

  // XCD-aware bijective swizzle (m204), m-fastest within each XCD chunk:
  // blocks sharing a W-panel land contiguously on one XCD's L2.
  const int nwg = gridDim.x * gridDim.y;
  const int bidl = blockIdx.y * gridDim.x + blockIdx.x;
  const int xcd = bidl & 7;
  const int q8 = nwg >> 3, r8 = nwg & 7;
  const int lin = (xcd < r8 ? xcd * (q8 + 1)
                            : r8 * (q8 + 1) + (xcd - r8) * q8) + (bidl >> 3);
  const int m0 = (lin % gridDim.x) * BM;
  const int n0 = (lin / gridDim.x) * BN;

  // Staging: pass p, thread t writes LDS bytes [p*4096 + t*16, +16)
  // == row (p*32 + t/8), 16B slot (t&7) of a 128B row.
  // Swizzle: LDS slot s of row r holds global k-block (s ^ (r&7)).
  const int srow = tid >> 3;       // 0..31
  const int slot = tid & 7;
  const unsigned short* gA[PA];
  const unsigned short* gB[PB];
#pragma unroll
  for (int p = 0; p < PA; ++p) {
    int row = p * 32 + srow;
    int kblk = (slot ^ (row & 7)) << 3;           // element offset in K-tile
    gA[p] = A + (size_t)(m0 + row) * K + kblk;    // m0+row < M (M%BM==0)
  }
#pragma unroll
  for (int p = 0; p < PB; ++p) {
    int row = p * 32 + srow;
    int kblk = (slot ^ (row & 7)) << 3;
    int wrow = n0 + row;
    if (wrow >= N) wrow = N - 1;                  // clamp load; store guarded
    gB[p] = W + (size_t)wrow * K + kblk;
  }

  f32x4_t acc[FM][FN];
#pragma unroll
  for (int i = 0; i < FM; ++i)
#pragma unroll
    for (int j = 0; j < FN; ++j) acc[i][j] = (f32x4_t){0.f, 0.f, 0.f, 0.f};

  // Fragment rows: wr*WTM + i*16 + lr -> (row&7) == (lr&7) (all mult of 8)
  const int xmask = (lr & 7) << 4;                // byte-XOR swizzle mask
  const int NKT = K >> 6;

  auto stage = [&](int buf, int kt) {
    const int k0 = kt << 6;
#pragma unroll
    for (int p = 0; p < PA; ++p)
      gload_lds16(gA[p] + k0, (char*)(Asb + buf * BM * 64) + p * 4096 +
                                  wave * 1024);
#pragma unroll
    for (int p = 0; p < PB; ++p)
      gload_lds16(gB[p] + k0, (char*)(Bsb + buf * BN * 64) + p * 4096 +
                                  wave * 1024);
  };

  auto compute = [&](int buf) {
    const char* Ab = (const char*)(Asb + buf * BM * 64);
    const char* Bb = (const char*)(Bsb + buf * BN * 64);
#pragma unroll
    for (int ks = 0; ks < 2; ++ks) {
      const int kb = (ks << 6) + (kq << 1);       // byte offset of k-block
      bf16x8_t a[FM], b[FN];
#pragma unroll
      for (int i = 0; i < FM; ++i)
        a[i] = *(const bf16x8_t*)(Ab + (wr * WTM + i * 16 + lr) * 128 +
                                  (kb ^ xmask));
#pragma unroll
      for (int j = 0; j < FN; ++j)
        b[j] = *(const bf16x8_t*)(Bb + (wc * WTN + j * 16 + lr) * 128 +
                                  (kb ^ xmask));
#pragma unroll
      for (int i = 0; i < FM; ++i)
#pragma unroll
        for (int j = 0; j < FN; ++j)
          acc[i][j] =
              __builtin_amdgcn_mfma_f32_16x16x32_bf16(a[i], b[j], acc[i][j],
                                                      0, 0, 0);
    }
  };

  if (DBUF) {
    // 2-phase counted-vmcnt pipeline (measured neutral, kept as verified).
    stage(0, 0);
    int cur = 0;
    for (int kt = 0; kt < NKT; ++kt) {
      if (kt + 1 < NKT) {
        stage(cur ^ 1, kt + 1);
        if constexpr (PA + PB == 4)
          asm volatile("s_waitcnt vmcnt(4)" ::: "memory");
        else
          asm volatile("s_waitcnt vmcnt(8)" ::: "memory");
      } else {
        asm volatile("s_waitcnt vmcnt(0)" ::: "memory");
      }
      __builtin_amdgcn_s_barrier();               // S1: tile kt visible
      __builtin_amdgcn_sched_barrier(0);
      compute(cur);
      __builtin_amdgcn_sched_barrier(0);
      __builtin_amdgcn_s_barrier();               // S2: reads of buf done
      cur ^= 1;
    }
  } else {
    // Single-buffer 2-barrier loop (proven baseline).
    for (int kt = 0; kt < NKT; ++kt) {
      if (kt) __syncthreads();
      stage(0, kt);
      __syncthreads();                            // drains vmcnt
      compute(0);
    }
  }

  if constexpr (ACT == 2) {
    // Full-line nontemporal C stores via LDS transpose (bias assumed null).
    // Two 64-row passes; each pass: frag->LDS by the owning 2 waves, then
    // all 256 threads stream 16B/lane of contiguous data (1024B/instr = 8
    // full 128B lines) with nt so the 412MB C stream doesn't evict W in L2.
    float* C = (float*)Cv;
    float (*cs)[128] = (float(*)[128])smem;
    const int hi4 = (lane >> 4) << 2;
#pragma unroll
    for (int pass = 0; pass < 2; ++pass) {
      __syncthreads();  // staging reads (pass0) / prior-pass stores done
      if (wr == pass) {
#pragma unroll
        for (int i = 0; i < FM; ++i)
#pragma unroll
          for (int j = 0; j < FN; ++j)
#pragma unroll
            for (int r = 0; r < 4; ++r)
              cs[i * 16 + hi4 + r][wc * 64 + j * 16 + lr] = acc[i][j][r];
      }
      __syncthreads();
#pragma unroll
      for (int s8 = 0; s8 < 8; ++s8) {
        int slotc = s8 * 256 + tid;     // 0..2047
        int row = slotc >> 5;           // 64 rows, 32 f32x4-slots each
        int c4 = (slotc & 31) << 2;
        int gcol = n0 + c4;
        f32x4_t v = *(const f32x4_t*)&cs[row][c4];
        float* cp = C + (size_t)(m0 + pass * 64 + row) * N + gcol;
        if (gcol + 3 < N) {
          __builtin_nontemporal_store(v, (f32x4_t*)cp);
        } else {
#pragma unroll
          for (int e = 0; e < 4; ++e)
            if (gcol + e < N) cp[e] = v[e];
        }
      }
    }
    return;
  }

  // C/D layout (m89/m91): col=lane&15, row=(lane>>4)*4+r
  const int crow0 = m0 + wr * WTM + ((lane >> 4) << 2);
#pragma unroll
  for (int i = 0; i < FM; ++i) {
    int crow = crow0 + i * 16;
#pragma unroll
    for (int j = 0; j < FN; ++j) {
      int col = n0 + wc * WTN + j * 16 + lr;
      if (col >= N) continue;
      float bv = bias ? bias[col] : 0.0f;
#pragma unroll
      for (int r = 0; r < 4; ++r) {
        float v = acc[i][j][r] + bv;
        if (ACT == 0) {
          ((float*)Cv)[(size_t)(crow + r) * N + col] = v;
        } else {
          float g = 0.5f * v * (1.f + erff(v * 0.7071067811865476f));
          ((unsigned short*)Cv)[(size_t)(crow + r) * N + col] = f2bf(g);
        }
      }
    }
  }
}

// ---------------------------------------------------------------------------
// Fallback GEMM (f32 W, inline cvt) — only used if workspace can't hold tok_b16.
template <int W_IS_F32>
__global__ __launch_bounds__(256) void gemm_bt_kernel(
    const unsigned short* __restrict__ A, const void* __restrict__ W,
    const float* __restrict__ bias, float* __restrict__ C,
    int M, int N, int K) {
  int wave = threadIdx.x >> 6;
  int lane = threadIdx.x & 63;
  int lr = lane & 15;
  int kq = (lane >> 4) << 3;
  int n0 = blockIdx.x << 6;
  int m0 = blockIdx.y << 6;
  int row = m0 + wave * 16 + lr;

  const unsigned short* arow = A + (size_t)row * K + kq;
  const unsigned short* browb[4];
  const float* browf[4];
#pragma unroll
  for (int nt = 0; nt < 4; ++nt) {
    int col = n0 + nt * 16 + lr;
    if (col >= N) col = N - 1;
    if (W_IS_F32) browf[nt] = (const float*)W + (size_t)col * K + kq;
    else          browb[nt] = (const unsigned short*)W + (size_t)col * K + kq;
  }

  f32x4_t acc[4] = {{0.f, 0.f, 0.f, 0.f},
                    {0.f, 0.f, 0.f, 0.f},
                    {0.f, 0.f, 0.f, 0.f},
                    {0.f, 0.f, 0.f, 0.f}};

  for (int k0 = 0; k0 < K; k0 += 32) {
    bf16x8_t a = *(const bf16x8_t*)(arow + k0);
#pragma unroll
    for (int nt = 0; nt < 4; ++nt) {
      bf16x8_t bfr;
      if (W_IS_F32) {
        f32x4_t w0 = *(const f32x4_t*)(browf[nt] + k0);
        f32x4_t w1 = *(const f32x4_t*)(browf[nt] + k0 + 4);
#pragma unroll
        for (int j = 0; j < 4; ++j) {
          bfr[j]     = (short)f2bf(w0[j]);
          bfr[4 + j] = (short)f2bf(w1[j]);
        }
      } else {
        bfr = *(const bf16x8_t*)(browb[nt] + k0);
      }
      acc[nt] = __builtin_amdgcn_mfma_f32_16x16x32_bf16(a, bfr, acc[nt], 0, 0, 0);
    }
  }

  int crow = m0 + wave * 16 + ((lane >> 4) << 2);
#pragma unroll
  for (int nt = 0; nt < 4; ++nt) {
    int col = n0 + nt * 16 + lr;
    if (col >= N) continue;
    float bv = bias ? bias[col] : 0.0f;
#pragma unroll
    for (int r = 0; r < 4; ++r) {
      float v = acc[nt][r] + bv;
      C[(size_t)(crow + r) * N + col] = v;
    }
  }
}

// ---------------------------------------------------------------------------
// MFMA flash attention. Block = 256 thr (4 waves) handles a 64-row Q-tile of
// one (b,h). Wave w owns q-rows qt0+w*16..+15. K-chunks of 64 staged in LDS:
// K as [key][d] bf16 (rows 144B, 16B-aligned), V transposed as [d][key] so the
// PV B-frag read (8 consecutive keys at fixed d) is a contiguous ds_read_b128.
// Online softmax in f32 on the C-frag layout (col=lane&15, row=hi*4+r);
// row-reduce via shfl_xor {8,4,2,1} within the 16-lane column group.
// P transits per-wave LDS to re-shape C-layout -> A-frag layout.
// Mask: key in [q - rel[q], q]; rel (cummax) is non-decreasing, so the tile's
// chunk range [align64(klo[qt0]) .. qt0+63] covers every row's valid keys.
__global__ __launch_bounds__(256) void attn_mfma_kernel(
    const float* __restrict__ qkv, const int* __restrict__ rel,
    unsigned short* __restrict__ obf) {
  __shared__ __align__(16) unsigned short k_s[64][72];
  __shared__ __align__(16) unsigned short v_s[64][72];
  __shared__ __align__(16) unsigned short p_s[4][16][72];

  const int tid = threadIdx.x;
  const int wave = tid >> 6, lane = tid & 63;
  const int lr = lane & 15, hi = lane >> 4;

  const int bid = blockIdx.x;
  const int qt0 = (bid & 15) << 6;     // L/64 = 16 q-tiles
  const int h = (bid >> 4) % H_;
  const int b = bid / (16 * H_);
  const int boff = b * L_;

  // Q fragments (f32 -> bf16): A-frag m=lane&15 -> q-row, k=hi*8+j -> d
  const int qrow = qt0 + wave * 16 + lr;
  const float* qp = qkv + (size_t)(boff + qrow) * TD_ + h * HD_ + hi * 8;
  bf16x8_t aq[2];
#pragma unroll
  for (int ks = 0; ks < 2; ++ks) {
    f32x4_t q0 = *(const f32x4_t*)(qp + ks * 32);
    f32x4_t q1 = *(const f32x4_t*)(qp + ks * 32 + 4);
#pragma unroll
    for (int j = 0; j < 4; ++j) {
      aq[ks][j] = (short)f2bf(q0[j]);
      aq[ks][4 + j] = (short)f2bf(q1[j]);
    }
  }

  // klo for the 4 accumulator rows this lane owns (C rows = hi*4+r)
  int klo_r[4];
#pragma unroll
  for (int r = 0; r < 4; ++r) {
    int qr = qt0 + wave * 16 + hi * 4 + r;
    klo_r[r] = qr - rel[boff + qr];
  }
  const int base0 = ((qt0 - rel[boff + qt0]) >> 6) << 6;

  float m_r[4] = {-1e30f, -1e30f, -1e30f, -1e30f};
  float l_r[4] = {0.f, 0.f, 0.f, 0.f};
  f32x4_t o_acc[4];
#pragma unroll
  for (int dt = 0; dt < 4; ++dt) o_acc[dt] = (f32x4_t){0.f, 0.f, 0.f, 0.f};

  const int skey = tid >> 2;           // staging: key row 0..63
  const int sdq = (tid & 3) << 4;      // staging: d quarter 0/16/32/48

  for (int base = base0; base <= qt0 + 63; base += 64) {
    __syncthreads();                   // prev chunk's LDS reads done
    // ---- stage K [key][d] and V^T [d][key], f32 -> bf16 (16 elems/thread ea)
    const float* kp = qkv + (size_t)(boff + base + skey) * TD_ + D_ +
                      h * HD_ + sdq;
    f32x4_t k0 = *(const f32x4_t*)(kp);
    f32x4_t k1 = *(const f32x4_t*)(kp + 4);
    f32x4_t k2 = *(const f32x4_t*)(kp + 8);
    f32x4_t k3 = *(const f32x4_t*)(kp + 12);
    bf16x8_t kb0, kb1;
#pragma unroll
    for (int j = 0; j < 4; ++j) {
      kb0[j] = (short)f2bf(k0[j]); kb0[4 + j] = (short)f2bf(k1[j]);
      kb1[j] = (short)f2bf(k2[j]); kb1[4 + j] = (short)f2bf(k3[j]);
    }
    *(bf16x8_t*)&k_s[skey][sdq] = kb0;
    *(bf16x8_t*)&k_s[skey][sdq + 8] = kb1;

    const float* vp = kp + D_;
    f32x4_t v0 = *(const f32x4_t*)(vp);
    f32x4_t v1 = *(const f32x4_t*)(vp + 4);
    f32x4_t v2 = *(const f32x4_t*)(vp + 8);
    f32x4_t v3 = *(const f32x4_t*)(vp + 12);
#pragma unroll
    for (int j = 0; j < 4; ++j) {
      v_s[sdq + j][skey]      = f2bf(v0[j]);
      v_s[sdq + 4 + j][skey]  = f2bf(v1[j]);
      v_s[sdq + 8 + j][skey]  = f2bf(v2[j]);
      v_s[sdq + 12 + j][skey] = f2bf(v3[j]);
    }
    __syncthreads();

    // ---- S = Q K^T : per wave 16 q-rows x 64 keys (4 tiles x 2 k-steps)
    f32x4_t s[4];
#pragma unroll
    for (int tj = 0; tj < 4; ++tj) {
      s[tj] = (f32x4_t){0.f, 0.f, 0.f, 0.f};
#pragma unroll
      for (int ks = 0; ks < 2; ++ks) {
        bf16x8_t kb = *(const bf16x8_t*)&k_s[tj * 16 + lr][ks * 32 + hi * 8];
        s[tj] = __builtin_amdgcn_mfma_f32_16x16x32_bf16(aq[ks], kb, s[tj],
                                                        0, 0, 0);
      }
    }

    // ---- online softmax (f32)
    float al_r[4];
#pragma unroll
    for (int r = 0; r < 4; ++r) {
      const int qr = qt0 + wave * 16 + hi * 4 + r;
#pragma unroll
      for (int tj = 0; tj < 4; ++tj) {
        int key = base + tj * 16 + lr;
        bool valid = (key >= klo_r[r]) && (key <= qr);
        s[tj][r] = valid ? s[tj][r] * 0.125f : -1e30f;
      }
      float cm = fmaxf(fmaxf(s[0][r], s[1][r]), fmaxf(s[2][r], s[3][r]));
#pragma unroll
      for (int off = 8; off; off >>= 1)
        cm = fmaxf(cm, __shfl_xor(cm, off, 64));
      float mn = fmaxf(m_r[r], cm);
      al_r[r] = __expf(m_r[r] - mn);   // both -1e30 -> exp(0)=1, o is 0 anyway
      float rs = 0.f;
#pragma unroll
      for (int tj = 0; tj < 4; ++tj) {
        float p = (s[tj][r] < -1e29f) ? 0.f : __expf(s[tj][r] - mn);
        s[tj][r] = p;
        rs += p;
      }
#pragma unroll
      for (int off = 8; off; off >>= 1) rs += __shfl_xor(rs, off, 64);
      l_r[r] = l_r[r] * al_r[r] + rs;
      m_r[r] = mn;
    }

    // ---- P (bf16) -> per-wave LDS (C-layout write, A-frag read); rescale O
#pragma unroll
    for (int r = 0; r < 4; ++r) {
#pragma unroll
      for (int tj = 0; tj < 4; ++tj)
        p_s[wave][hi * 4 + r][tj * 16 + lr] = f2bf(s[tj][r]);
#pragma unroll
      for (int dt = 0; dt < 4; ++dt) o_acc[dt][r] *= al_r[r];
    }
    // DS ops within a wave complete in order; compiler inserts lgkmcnt waits.

    // ---- O += P @ V  (B-frag from V^T layout: row d, 8 consecutive keys)
#pragma unroll
    for (int ks = 0; ks < 2; ++ks) {
      bf16x8_t pa = *(const bf16x8_t*)&p_s[wave][lr][ks * 32 + hi * 8];
#pragma unroll
      for (int dt = 0; dt < 4; ++dt) {
        bf16x8_t vb = *(const bf16x8_t*)&v_s[dt * 16 + lr][ks * 32 + hi * 8];
        o_acc[dt] = __builtin_amdgcn_mfma_f32_16x16x32_bf16(pa, vb, o_acc[dt],
                                                            0, 0, 0);
      }
    }
  }

  // ---- normalize and store (bf16)
#pragma unroll
  for (int r = 0; r < 4; ++r) {
    float inv = 1.f / l_r[r];
    int qr = qt0 + wave * 16 + hi * 4 + r;
    unsigned short* op = obf + (size_t)(boff + qr) * D_ + h * HD_ + lr;
#pragma unroll
    for (int dt = 0; dt < 4; ++dt)
      op[dt * 16] = f2bf(o_acc[dt][r] * inv);
  }
}

// ---------------------------------------------------------------------------
// x = LN(x + t)*w + b; write f32 and bf16 shadow. One block (256 thr) per row.
__device__ __forceinline__ float block_reduce_sum_256(float v, float* sbuf) {
#pragma unroll
  for (int off = 32; off; off >>= 1) v += __shfl_xor(v, off, 64);
  if ((threadIdx.x & 63) == 0) sbuf[threadIdx.x >> 6] = v;
  __syncthreads();
  float r = sbuf[0] + sbuf[1] + sbuf[2] + sbuf[3];
  __syncthreads();
  return r;
}

__global__ __launch_bounds__(256) void add_ln_kernel(
    const float* __restrict__ x, const float* __restrict__ t,
    const float* __restrict__ w, const float* __restrict__ b,
    float* __restrict__ xo, unsigned short* __restrict__ xbo) {
  __shared__ float sbuf[4];
  size_t base = (size_t)blockIdx.x * D_;
  float v[3];
  float s = 0.f;
#pragma unroll
  for (int i = 0; i < 3; ++i) {
    int idx = threadIdx.x + i * 256;
    v[i] = x[base + idx] + t[base + idx];
    s += v[i];
  }
  float mean = block_reduce_sum_256(s, sbuf) * (1.f / D_);
  float vs = 0.f;
#pragma unroll
  for (int i = 0; i < 3; ++i) {
    float d = v[i] - mean;
    vs += d * d;
  }
  float var = block_reduce_sum_256(vs, sbuf) * (1.f / D_);
  float rstd = rsqrtf(var + 1e-5f);
#pragma unroll
  for (int i = 0; i < 3; ++i) {
    int idx = threadIdx.x + i * 256;
    float o = (v[i] - mean) * rstd * w[idx] + b[idx];
    xo[base + idx] = o;
    xbo[base + idx] = f2bf(o);
  }
}

// ---------------------------------------------------------------------------
extern "C" void kernel_launch(void* const* d_in, const int* in_sizes, int n_in,
                              void* d_out, int out_size, void* d_ws, size_t ws_size,
                              hipStream_t stream) {
  const int* ids       = (const int*)d_in[0];
  const float* tok     = (const float*)d_in[1];
  const float* pos     = (const float*)d_in[2];
  const float* qkv_w   = (const float*)d_in[3];
  const float* qkv_b   = (const float*)d_in[4];
  const float* out_w   = (const float*)d_in[5];
  const float* out_b   = (const float*)d_in[6];
  const float* ln1_w   = (const float*)d_in[7];
  const float* ln1_b   = (const float*)d_in[8];
  const float* ln2_w   = (const float*)d_in[9];
  const float* ln2_b   = (const float*)d_in[10];
  const float* ff1_w   = (const float*)d_in[11];
  const float* ff2_w   = (const float*)d_in[13];
  const float* ff2_b   = (const float*)d_in[14];
  const float* ff1_b   = (const float*)d_in[12];

  char* ws = (char*)d_ws;
  size_t off = 0;
  auto alloc = [&](size_t bytes) {
    void* p = ws + off;
    off = (off + bytes + 255) & ~(size_t)255;
    return p;
  };
  int* rel            = (int*)alloc((size_t)BL_ * 4);
  float* x            = (float*)alloc((size_t)BL_ * D_ * 4);
  unsigned short* xb  = (unsigned short*)alloc((size_t)BL_ * D_ * 2);
  // qkvbuf (live qkv->attn) only user of big now
  float* big          = (float*)alloc((size_t)BL_ * DFF_ * 4);
  float* qkvbuf       = big;
  unsigned short* obf = (unsigned short*)alloc((size_t)BL_ * D_ * 2);
  float* t            = (float*)alloc((size_t)BL_ * D_ * 4);
  unsigned short* hb  = (unsigned short*)alloc((size_t)BL_ * DFF_ * 2);
  // bf16 weight copies (both layers)
  unsigned short* qkvw_b16 = (unsigned short*)alloc((size_t)NL_ * TD_ * D_ * 2);
  unsigned short* outw_b16 = (unsigned short*)alloc((size_t)NL_ * D_ * D_ * 2);
  unsigned short* ff1w_b16 = (unsigned short*)alloc((size_t)NL_ * DFF_ * D_ * 2);
  unsigned short* ff2w_b16 = (unsigned short*)alloc((size_t)NL_ * D_ * DFF_ * 2);
  size_t base_need = off;
  unsigned short* tok_b16 = (unsigned short*)alloc((size_t)V_ * D_ * 2);
  bool have_tok = (off <= ws_size);
  (void)base_need;

  auto cvt = [&](const float* in, unsigned short* out, size_t n) {
    int n4 = (int)(n / 4);
    cvt_kernel<<<(n4 + 255) / 256, 256, 0, stream>>>(in, out, n4);
  };
  cvt(qkv_w, qkvw_b16, (size_t)NL_ * TD_ * D_);
  cvt(out_w, outw_b16, (size_t)NL_ * D_ * D_);
  cvt(ff1_w, ff1w_b16, (size_t)NL_ * DFF_ * D_);
  cvt(ff2_w, ff2w_b16, (size_t)NL_ * D_ * DFF_);
  if (have_tok) cvt(tok, tok_b16, (size_t)V_ * D_);

  prep_kernel<<<(BL_ + 255) / 256, 256, 0, stream>>>(ids, rel);
  embed_kernel<<<(BL_ * D_ + 255) / 256, 256, 0, stream>>>(ids, tok, pos, rel, x, xb);

  // Tile choice: 128^2 single-buffer for big grids; 64^2 + DBUF pipeline
  // when the 128^2 grid would under-fill the machine (<384 blocks).
  auto gemm = [&](const unsigned short* A, const unsigned short* W,
                  const float* bias, float* C, int M, int N, int K) {
    int blocks128 = (M / 128) * ((N + 127) / 128);
    if ((N % 64) == 0 && blocks128 < 384) {
      gemm_tile_kernel<64, 64, 0, 1>
          <<<dim3(M / 64, N / 64), 256, 0, stream>>>(A, W, bias, (void*)C,
                                                     M, N, K);
    } else {
      gemm_tile_kernel<128, 128, 0, 0>
          <<<dim3(M / 128, (N + 127) / 128), 256, 0, stream>>>(
              A, W, bias, (void*)C, M, N, K);
    }
  };

  for (int l = 0; l < NL_; ++l) {
    // qkv = xb @ qkv_w[l].T + qkv_b[l]   [BL, 3D]
    gemm(xb, qkvw_b16 + (size_t)l * TD_ * D_, qkv_b + (size_t)l * TD_, qkvbuf,
         BL_, TD_, D_);
    // attention -> obf (bf16)
    attn_mfma_kernel<<<B_ * H_ * (L_ / 64), 256, 0, stream>>>(qkvbuf, rel, obf);
    // t = obf @ out_w[l].T + out_b[l]
    gemm(obf, outw_b16 + (size_t)l * D_ * D_, out_b + (size_t)l * D_, t,
         BL_, D_, D_);
    // x = LN(x + t)
    add_ln_kernel<<<BL_, 256, 0, stream>>>(x, t, ln1_w + l * D_, ln1_b + l * D_, x, xb);
    // hb = gelu(xb @ ff1_w[l].T + ff1_b[l]) in bf16, fused epilogue [BL, DFF]
    gemm_tile_kernel<128, 128, 1, 0>
        <<<dim3(BL_ / 128, DFF_ / 128), 256, 0, stream>>>(
            xb, ff1w_b16 + (size_t)l * DFF_ * D_, ff1_b + (size_t)l * DFF_,
            (void*)hb, BL_, DFF_, D_);
    // t = hb @ ff2_w[l].T + ff2_b[l]
    gemm(hb, ff2w_b16 + (size_t)l * D_ * DFF_, ff2_b + (size_t)l * D_, t,
         BL_, D_, DFF_);
    // x = LN(x + h)
    add_ln_kernel<<<BL_, 256, 0, stream>>>(x, t, ln2_w + l * D_, ln2_b + l * D_, x, xb);
  }

  // logits = xb @ tok_emb.T -> f32 d_out [BL, V]: 128^2 single-buffer with
  // ACT=2 epilogue (LDS transpose + full-line nt stores; bias must be null).
  if (have_tok) {
    gemm_tile_kernel<128, 128, 2, 0>
        <<<dim3(BL_ / 128, (V_ + 127) / 128), 256, 0, stream>>>(
            xb, tok_b16, nullptr, (void*)d_out, BL_, V_, D_);
  } else {
    gemm_bt_kernel<1><<<dim3((V_ + 63) / 64, BL_ / 64), 256, 0, stream>>>(
        xb, tok, nullptr, (float*)d_out, BL_, V_, D_);
  }
}